// Round 1
// 1021.081 us; speedup vs baseline: 1.0579x; 1.0579x over previous
//
#include <hip/hip_runtime.h>
#include <hip/hip_bf16.h>

#define N_NODES 50000
#define N_EDGES 800000
#define F_INN   768
#define HID     128
#define N_CLS   9
#define ETOT    (N_EDGES + N_NODES)
#define BN_EPS  1e-5f

typedef __hip_bfloat16 bf16;
typedef __attribute__((ext_vector_type(8))) short bf16x8;
typedef __attribute__((ext_vector_type(4))) float f32x4;

__device__ __forceinline__ float leaky(float v, float s) { return v >= 0.0f ? v : s * v; }
__device__ __forceinline__ int clampn(int s) {
  return ((unsigned)s < (unsigned)N_NODES) ? s : 0;
}
__device__ __forceinline__ short f2bs(float f) {
  bf16 h = __float2bfloat16(f);
  return __builtin_bit_cast(short, h);
}
__device__ __forceinline__ float bs2f(unsigned short u) {
  unsigned v = ((unsigned)u) << 16;
  return __builtin_bit_cast(float, v);
}

// ---------------- pack W0^T, Wm^T to bf16 [n][k] ----------------
__global__ void k_pack(const float* __restrict__ W0, const float* __restrict__ Wm,
                       short* __restrict__ W0T, short* __restrict__ WmT) {
  int i = blockIdx.x * blockDim.x + threadIdx.x;
  if (i < F_INN * HID) {
    int n = i / F_INN, k = i % F_INN;
    W0T[i] = f2bs(W0[k * HID + n]);
  } else if (i < F_INN * HID + 3 * HID * HID) {
    int j = i - F_INN * HID;
    int l = j / (HID * HID), rem = j % (HID * HID);
    int n = rem / HID, k = rem % HID;
    WmT[j] = f2bs(Wm[(l * HID + k) * HID + n]);
  }
}

__global__ void k_zero(float* p, int n) {
  int i = blockIdx.x * blockDim.x + threadIdx.x;
  if (i < n) p[i] = 0.0f;
}

// ---------------- CSR build ----------------
__global__ void k_init_deg(int* fill) {
  int i = blockIdx.x * blockDim.x + threadIdx.x;
  if (i < N_NODES) fill[i] = 1;  // self-loop
}

__global__ void k_count(const int* __restrict__ dst, int* fill) {
  int e = blockIdx.x * blockDim.x + threadIdx.x;
  if (e < N_EDGES) atomicAdd(&fill[clampn(dst[e])], 1);
}

__global__ void k_scan(int* fill, int* row_ptr) {
  __shared__ int sh[1024];
  int tid = threadIdx.x;
  int carry = 0;
  for (int base = 0; base < N_NODES; base += 1024) {
    int i = base + tid;
    int v = (i < N_NODES) ? fill[i] : 0;
    if (i < N_NODES) fill[i] = 0;
    sh[tid] = v;
    __syncthreads();
    for (int off = 1; off < 1024; off <<= 1) {
      int t = (tid >= off) ? sh[tid - off] : 0;
      __syncthreads();
      sh[tid] += t;
      __syncthreads();
    }
    if (i < N_NODES) row_ptr[i] = carry + sh[tid] - v;
    int tot = sh[1023];
    __syncthreads();
    carry += tot;
  }
  if (tid == 0) row_ptr[N_NODES] = carry;
}

__global__ void k_place(const int* __restrict__ src, const int* __restrict__ dst,
                        const int* __restrict__ row_ptr, int* fill, int* csr_src) {
  int id = blockIdx.x * blockDim.x + threadIdx.x;
  if (id >= ETOT) return;
  int s, d;
  if (id < N_EDGES) { s = clampn(src[id]); d = clampn(dst[id]); }
  else { s = id - N_EDGES; d = s; }
  int p = atomicAdd(&fill[d], 1);
  csr_src[row_ptr[d] + p] = s;
}

// ---------------- MFMA GEMM: fully-unrolled K loop, static prefetch rings ----------------
// Previous version compiled to 40 VGPRs (compiler chased occupancy the grid can't
// deliver) -> zero pipelining -> 600 GB/s on a compulsory X stream. Here:
//   - __launch_bounds__(128,2): 256-VGPR cap, 128-thread blocks halve the grid tail
//   - depth-4 X prefetch ring (static indices via full unroll -> stays in VGPRs)
//   - double-buffered B fragments (next step's 8 tiles load during current MFMAs)
template <int K, bool BN>
__global__ __launch_bounds__(128, 2)
void k_gemm_mfma(const float* __restrict__ X, const short* __restrict__ BT,
                 const float* __restrict__ scale, const float* __restrict__ shift,
                 const float* __restrict__ a_s, const float* __restrict__ a_d,
                 short* __restrict__ hb, float* __restrict__ asrc,
                 float* __restrict__ adst) {
  int wave = (blockIdx.x * blockDim.x + threadIdx.x) >> 6;
  if (wave >= N_NODES / 16) return;
  int lane = threadIdx.x & 63;
  int m = lane & 15, q = lane >> 4;
  int row0 = wave * 16;
  constexpr int NS = K / 32;
  constexpr int PFX = (NS < 4) ? NS : 4;
  f32x4 acc[8];
#pragma unroll
  for (int t = 0; t < 8; ++t) acc[t] = (f32x4){0.f, 0.f, 0.f, 0.f};
  const float* xrow = X + (size_t)(row0 + m) * K + q * 8;
  const short* brow = BT + (size_t)m * K + q * 8;

  // prologue: fill X ring + first B set
  float4 xp[PFX][2];
#pragma unroll
  for (int p = 0; p < PFX; ++p) {
    xp[p][0] = *(const float4*)(xrow + p * 32);
    xp[p][1] = *(const float4*)(xrow + p * 32 + 4);
  }
  bf16x8 bp[2][8];
#pragma unroll
  for (int t = 0; t < 8; ++t) bp[0][t] = *(const bf16x8*)(brow + (size_t)t * 16 * K);

#pragma unroll
  for (int s = 0; s < NS; ++s) {
    const int xc = s % PFX;   // static: loop fully unrolled
    const int bc = s & 1;
    if (s + 1 < NS) {         // prefetch next step's B fragments
#pragma unroll
      for (int t = 0; t < 8; ++t)
        bp[bc ^ 1][t] = *(const bf16x8*)(brow + (s + 1) * 32 + (size_t)t * 16 * K);
    }
    float xv[8];
    *(float4*)(xv)     = xp[xc][0];
    *(float4*)(xv + 4) = xp[xc][1];
    if (s + PFX < NS) {       // refill X ring slot PFX steps ahead
      xp[xc][0] = *(const float4*)(xrow + (s + PFX) * 32);
      xp[xc][1] = *(const float4*)(xrow + (s + PFX) * 32 + 4);
    }
    if (BN) {
      float sc[8], sf[8];
      *(float4*)(sc)     = *(const float4*)(scale + s * 32 + q * 8);
      *(float4*)(sc + 4) = *(const float4*)(scale + s * 32 + q * 8 + 4);
      *(float4*)(sf)     = *(const float4*)(shift + s * 32 + q * 8);
      *(float4*)(sf + 4) = *(const float4*)(shift + s * 32 + q * 8 + 4);
#pragma unroll
      for (int j = 0; j < 8; ++j) xv[j] = leaky(xv[j] * sc[j] + sf[j], 0.1f);
    }
    bf16x8 a;
#pragma unroll
    for (int j = 0; j < 8; ++j) a[j] = f2bs(xv[j]);
#pragma unroll
    for (int t = 0; t < 8; ++t)
      acc[t] = __builtin_amdgcn_mfma_f32_16x16x32_bf16(a, bp[bc][t], acc[t], 0, 0, 0);
  }
  float sr[4] = {0.f, 0.f, 0.f, 0.f}, dr[4] = {0.f, 0.f, 0.f, 0.f};
#pragma unroll
  for (int t = 0; t < 8; ++t) {
    float av = a_s[t * 16 + m], dv = a_d[t * 16 + m];
#pragma unroll
    for (int r = 0; r < 4; ++r) {
      float c = acc[t][r];
      hb[(size_t)(row0 + q * 4 + r) * HID + t * 16 + m] = f2bs(c);
      sr[r] += c * av;
      dr[r] += c * dv;
    }
  }
#pragma unroll
  for (int r = 0; r < 4; ++r) {
#pragma unroll
    for (int off = 1; off < 16; off <<= 1) {
      sr[r] += __shfl_xor(sr[r], off);
      dr[r] += __shfl_xor(dr[r], off);
    }
  }
  if (m == 0) {
#pragma unroll
    for (int r = 0; r < 4; ++r) {
      asrc[row0 + q * 4 + r] = sr[r];
      adst[row0 + q * 4 + r] = dr[r];
    }
  }
}

// ---------------- GAT aggregation (H=128): one wave per node ----------------
// Gather loop now 4-way unrolled: 4 independent (LDS idx -> global h row) chains
// in flight instead of 1 (avg degree ~17 serial iterations was latency-bound).
__global__ void k_agg128(const unsigned short* __restrict__ h, const float* __restrict__ asrc,
                         const float* __restrict__ adst, const int* __restrict__ row_ptr,
                         const int* __restrict__ csr_src, const float* __restrict__ bias,
                         const float* __restrict__ hres, const float* __restrict__ scale,
                         const float* __restrict__ shift, float* __restrict__ out) {
  __shared__ int   lds_ss[4][64];
  __shared__ float lds_ex[4][64];
  int wid = (blockIdx.x * blockDim.x + threadIdx.x) >> 6;
  int lane = threadIdx.x & 63;
  int w = (threadIdx.x >> 6) & 3;   // wave slot in block
  if (wid >= N_NODES) return;
  int c0 = 2 * lane;
  int beg = row_ptr[wid], end = row_ptr[wid + 1];
  float adsti = adst[wid];
  // pass A: lane-parallel max + butterfly reduce
  float mx = -1e30f;
  for (int cb = beg; cb < end; cb += 64) {
    int e = cb + lane;
    if (e < end) {
      int s = clampn(csr_src[e]);
      mx = fmaxf(mx, leaky(asrc[s] + adsti, 0.2f));
    }
  }
#pragma unroll
  for (int off = 1; off < 64; off <<= 1) mx = fmaxf(mx, __shfl_xor(mx, off));
  // pass B: lane-parallel exp -> LDS stage -> broadcast gather
  float z = 0.f, a0 = 0.f, a1 = 0.f;
  for (int cb = beg; cb < end; cb += 64) {
    int cnt = min(64, end - cb);
    int sl = 0;
    float ex = 0.f;
    if (lane < cnt) {
      sl = clampn(csr_src[cb + lane]);
      ex = __expf(leaky(asrc[sl] + adsti, 0.2f) - mx);
    }
    lds_ss[w][lane] = sl;
    lds_ex[w][lane] = ex;
    __builtin_amdgcn_wave_barrier();   // pin LDS write before reads (wave-private region)
    float zp = ex;
#pragma unroll
    for (int off = 1; off < 64; off <<= 1) zp += __shfl_xor(zp, off);
    z += zp;
    int j = 0;
    for (; j + 4 <= cnt; j += 4) {
      int s0 = lds_ss[w][j],     s1 = lds_ss[w][j + 1];
      int s2 = lds_ss[w][j + 2], s3 = lds_ss[w][j + 3];
      float e0 = lds_ex[w][j],     e1 = lds_ex[w][j + 1];
      float e2 = lds_ex[w][j + 2], e3 = lds_ex[w][j + 3];
      unsigned v0 = *(const unsigned*)(h + (size_t)s0 * HID + c0);
      unsigned v1 = *(const unsigned*)(h + (size_t)s1 * HID + c0);
      unsigned v2 = *(const unsigned*)(h + (size_t)s2 * HID + c0);
      unsigned v3 = *(const unsigned*)(h + (size_t)s3 * HID + c0);
      a0 += e0 * bs2f((unsigned short)(v0 & 0xffffu));
      a1 += e0 * bs2f((unsigned short)(v0 >> 16));
      a0 += e1 * bs2f((unsigned short)(v1 & 0xffffu));
      a1 += e1 * bs2f((unsigned short)(v1 >> 16));
      a0 += e2 * bs2f((unsigned short)(v2 & 0xffffu));
      a1 += e2 * bs2f((unsigned short)(v2 >> 16));
      a0 += e3 * bs2f((unsigned short)(v3 & 0xffffu));
      a1 += e3 * bs2f((unsigned short)(v3 >> 16));
    }
    for (; j < cnt; ++j) {
      int ss = lds_ss[w][j];
      float exj = lds_ex[w][j];
      unsigned hv = *(const unsigned*)(h + (size_t)ss * HID + c0);
      a0 += exj * bs2f((unsigned short)(hv & 0xffffu));
      a1 += exj * bs2f((unsigned short)(hv >> 16));
    }
    __builtin_amdgcn_wave_barrier();   // keep next chunk's writes after these reads
  }
  float inv = (z > 0.0f) ? 1.0f / z : 0.0f;
  float o0 = a0 * inv + bias[c0];
  float o1 = a1 * inv + bias[c0 + 1];
  if (scale) {
    float2 hr = *(const float2*)(hres + (size_t)wid * HID + c0);
    o0 += leaky(hr.x * scale[c0] + shift[c0], 0.1f);
    o1 += leaky(hr.y * scale[c0 + 1] + shift[c0 + 1], 0.1f);
  }
  float2 o = {o0, o1};
  *(float2*)(out + (size_t)wid * HID + c0) = o;
}

// ---------------- BatchNorm stats ----------------
__global__ void k_bn_stats(const float* __restrict__ h, float* bnsum, float* bnsumsq) {
  int f = threadIdx.x;  // 128
  int r0 = blockIdx.x * 128;
  int r1 = min(r0 + 128, N_NODES);
  float s = 0.0f, s2 = 0.0f;
  for (int r = r0; r < r1; ++r) {
    float v = h[(size_t)r * HID + f];
    s += v;
    s2 += v * v;
  }
  atomicAdd(&bnsum[f], s);
  atomicAdd(&bnsumsq[f], s2);
}

__global__ void k_bn_final(const float* __restrict__ bnsum, const float* __restrict__ bnsumsq,
                           const float* __restrict__ gamma, const float* __restrict__ beta,
                           float* bnscale, float* bnshift) {
  int f = threadIdx.x;
  float mu = bnsum[f] / (float)N_NODES;
  float var = bnsumsq[f] / (float)N_NODES - mu * mu;
  var = fmaxf(var, 0.0f);
  float rstd = rsqrtf(var + BN_EPS);
  float g = gamma[f];
  bnscale[f] = g * rstd;
  bnshift[f] = beta[f] - mu * g * rstd;
}

// ---------------- final layer GEMM (BN fused) + alpha logits ----------------
__global__ void k_final_gemm(const float* __restrict__ h, const float* __restrict__ scale,
                             const float* __restrict__ shift, const float* __restrict__ W4,
                             const float* __restrict__ a4s, const float* __restrict__ a4d,
                             float* __restrict__ h4, float* __restrict__ asrc,
                             float* __restrict__ adst) {
  int row = (blockIdx.x * blockDim.x + threadIdx.x) >> 6;
  int lane = threadIdx.x & 63;
  if (row >= N_NODES) return;
  float t0 = leaky(h[(size_t)row * HID + lane] * scale[lane] + shift[lane], 0.1f);
  float t1 = leaky(h[(size_t)row * HID + 64 + lane] * scale[64 + lane] + shift[64 + lane], 0.1f);
  float myv = 0.0f, s = 0.0f, d = 0.0f;
#pragma unroll
  for (int c = 0; c < N_CLS; ++c) {
    float p = t0 * W4[lane * N_CLS + c] + t1 * W4[(lane + 64) * N_CLS + c];
#pragma unroll
    for (int m = 32; m; m >>= 1) p += __shfl_xor(p, m);
    s += p * a4s[c];
    d += p * a4d[c];
    if (lane == c) myv = p;
  }
  if (lane < N_CLS) h4[(size_t)row * N_CLS + lane] = myv;
  if (lane == 0) { asrc[row] = s; adst[row] = d; }
}

// ---------------- final aggregation (C=9) -> fp32 output ----------------
// Both edge loops 4-way unrolled for memory-level parallelism.
__global__ void k_final_agg(const float* __restrict__ h4, const float* __restrict__ asrc,
                            const float* __restrict__ adst, const int* __restrict__ row_ptr,
                            const int* __restrict__ csr_src, const float* __restrict__ b4,
                            float* __restrict__ out) {
  int wid = (blockIdx.x * blockDim.x + threadIdx.x) >> 6;
  int lane = threadIdx.x & 63;
  if (wid >= N_NODES) return;
  int beg = row_ptr[wid], end = row_ptr[wid + 1];
  float adsti = adst[wid];
  float mx = -1e30f;
  int e = beg;
  for (; e + 4 <= end; e += 4) {
    int s0 = clampn(csr_src[e]),     s1 = clampn(csr_src[e + 1]);
    int s2 = clampn(csr_src[e + 2]), s3 = clampn(csr_src[e + 3]);
    float v0 = leaky(asrc[s0] + adsti, 0.2f);
    float v1 = leaky(asrc[s1] + adsti, 0.2f);
    float v2 = leaky(asrc[s2] + adsti, 0.2f);
    float v3 = leaky(asrc[s3] + adsti, 0.2f);
    mx = fmaxf(mx, fmaxf(fmaxf(v0, v1), fmaxf(v2, v3)));
  }
  for (; e < end; ++e) {
    int s = clampn(csr_src[e]);
    mx = fmaxf(mx, leaky(asrc[s] + adsti, 0.2f));
  }
  float z = 0.0f, a = 0.0f;
  e = beg;
  for (; e + 4 <= end; e += 4) {
    int s0 = clampn(csr_src[e]),     s1 = clampn(csr_src[e + 1]);
    int s2 = clampn(csr_src[e + 2]), s3 = clampn(csr_src[e + 3]);
    float ex0 = __expf(leaky(asrc[s0] + adsti, 0.2f) - mx);
    float ex1 = __expf(leaky(asrc[s1] + adsti, 0.2f) - mx);
    float ex2 = __expf(leaky(asrc[s2] + adsti, 0.2f) - mx);
    float ex3 = __expf(leaky(asrc[s3] + adsti, 0.2f) - mx);
    z += (ex0 + ex1) + (ex2 + ex3);
    if (lane < N_CLS) {
      float h0 = h4[(size_t)s0 * N_CLS + lane];
      float h1 = h4[(size_t)s1 * N_CLS + lane];
      float h2 = h4[(size_t)s2 * N_CLS + lane];
      float h3 = h4[(size_t)s3 * N_CLS + lane];
      a += ex0 * h0 + ex1 * h1 + ex2 * h2 + ex3 * h3;
    }
  }
  for (; e < end; ++e) {
    int s = clampn(csr_src[e]);
    float ex = __expf(leaky(asrc[s] + adsti, 0.2f) - mx);
    z += ex;
    if (lane < N_CLS) a += ex * h4[(size_t)s * N_CLS + lane];
  }
  if (lane < N_CLS) {
    float o = (z > 0.0f) ? a / z : 0.0f;
    o = leaky(o + b4[lane], 0.1f);
    out[(size_t)wid * N_CLS + lane] = o;
  }
}

extern "C" void kernel_launch(void* const* d_in, const int* in_sizes, int n_in,
                              void* d_out, int out_size, void* d_ws, size_t ws_size,
                              hipStream_t stream) {
  const float* x   = (const float*)d_in[0];
  const int*   ei  = (const int*)d_in[1];
  const int*   src = ei;
  const int*   dst = ei + N_EDGES;
  const float* W0  = (const float*)d_in[4];
  const float* a0s = (const float*)d_in[5];
  const float* a0d = (const float*)d_in[6];
  const float* b0  = (const float*)d_in[7];
  const float* Wm  = (const float*)d_in[8];
  const float* ams = (const float*)d_in[9];
  const float* amd = (const float*)d_in[10];
  const float* bm  = (const float*)d_in[11];
  const float* W4  = (const float*)d_in[12];
  const float* a4s = (const float*)d_in[13];
  const float* a4d = (const float*)d_in[14];
  const float* b4  = (const float*)d_in[15];
  const float* gam = (const float*)d_in[16];
  const float* bet = (const float*)d_in[17];
  float* out = (float*)d_out;

  // ---- workspace layout (~45 MB) ----
  int* row_ptr   = (int*)d_ws;                    // 50001 (pad 50004)
  int* fill      = row_ptr + 50004;               // N
  int* csr_src   = fill + N_NODES;                // ETOT
  short* W0T     = (short*)(csr_src + ETOT);      // 98304
  short* WmT     = W0T + F_INN * HID;             // 49152
  short* bufA    = WmT + 3 * HID * HID;           // N*128 bf16 (pre-agg h)
  float* asrc    = (float*)(bufA + (size_t)N_NODES * HID);  // N
  float* adst    = asrc + N_NODES;                // N
  float* bnsum   = adst + N_NODES;                // 128
  float* bnsumsq = bnsum + HID;                   // 128
  float* bnscale = bnsumsq + HID;                 // 128
  float* bnshift = bnscale + HID;                 // 128
  float* h4      = bnshift + HID;                 // N*9
  float* bufB    = h4 + (size_t)N_NODES * N_CLS;  // N*128 fp32 (running h)

  const int B256 = 256;
  int gN    = (N_NODES + B256 - 1) / B256;
  int gE    = (N_EDGES + B256 - 1) / B256;
  int gET   = (ETOT + B256 - 1) / B256;
  int gWav  = (N_NODES + 3) / 4;
  int gMfma = (N_NODES / 16 + 1) / 2;   // 128-thread blocks, 2 waves each
  int gBN   = (N_NODES + 127) / 128;
  int gPack = (F_INN * HID + 3 * HID * HID + B256 - 1) / B256;

  // ---- pack weights + CSR ----
  k_pack<<<gPack, B256, 0, stream>>>(W0, Wm, W0T, WmT);
  k_init_deg<<<gN, B256, 0, stream>>>(fill);
  k_count<<<gE, B256, 0, stream>>>(dst, fill);
  k_scan<<<1, 1024, 0, stream>>>(fill, row_ptr);
  k_place<<<gET, B256, 0, stream>>>(src, dst, row_ptr, fill, csr_src);

  // ---- layer 0: h = GAT(x, W0, a0) + b0 -> bufB ----
  k_gemm_mfma<F_INN, false><<<gMfma, 128, 0, stream>>>(x, W0T, nullptr, nullptr,
                                                       a0s, a0d, bufA, asrc, adst);
  k_agg128<<<gWav, B256, 0, stream>>>((const unsigned short*)bufA, asrc, adst, row_ptr,
                                      csr_src, b0, nullptr, nullptr, nullptr, bufB);

  // ---- mid layers: t = leaky(bn(h),0.1) fused; h = GAT(t) + t ----
  for (int i = 0; i < 3; ++i) {
    k_zero<<<1, 256, 0, stream>>>(bnsum, 2 * HID);
    k_bn_stats<<<gBN, HID, 0, stream>>>(bufB, bnsum, bnsumsq);
    k_bn_final<<<1, HID, 0, stream>>>(bnsum, bnsumsq, gam + i * HID, bet + i * HID,
                                      bnscale, bnshift);
    k_gemm_mfma<HID, true><<<gMfma, 128, 0, stream>>>(bufB, WmT + i * HID * HID,
                                                      bnscale, bnshift,
                                                      ams + i * HID, amd + i * HID,
                                                      bufA, asrc, adst);
    k_agg128<<<gWav, B256, 0, stream>>>((const unsigned short*)bufA, asrc, adst, row_ptr,
                                        csr_src, bm + i * HID, bufB, bnscale, bnshift, bufB);
  }

  // ---- final: t = leaky(bn(h),0.1); out = leaky(GAT(t, W4), 0.1) ----
  k_zero<<<1, 256, 0, stream>>>(bnsum, 2 * HID);
  k_bn_stats<<<gBN, HID, 0, stream>>>(bufB, bnsum, bnsumsq);
  k_bn_final<<<1, HID, 0, stream>>>(bnsum, bnsumsq, gam + 3 * HID, bet + 3 * HID,
                                    bnscale, bnshift);
  k_final_gemm<<<gWav, B256, 0, stream>>>(bufB, bnscale, bnshift, W4, a4s, a4d,
                                          h4, asrc, adst);
  k_final_agg<<<gWav, B256, 0, stream>>>(h4, asrc, adst, row_ptr, csr_src, b4, out);
}

// Round 2
// 988.575 us; speedup vs baseline: 1.0927x; 1.0329x over previous
//
#include <hip/hip_runtime.h>
#include <hip/hip_bf16.h>

#define N_NODES 50000
#define N_EDGES 800000
#define F_INN   768
#define HID     128
#define N_CLS   9
#define ETOT    (N_EDGES + N_NODES)
#define BN_EPS  1e-5f

typedef __hip_bfloat16 bf16;
typedef __attribute__((ext_vector_type(8))) short bf16x8;
typedef __attribute__((ext_vector_type(4))) float f32x4;

__device__ __forceinline__ float leaky(float v, float s) { return v >= 0.0f ? v : s * v; }
__device__ __forceinline__ int clampn(int s) {
  return ((unsigned)s < (unsigned)N_NODES) ? s : 0;
}
__device__ __forceinline__ short f2bs(float f) {
  bf16 h = __float2bfloat16(f);
  return __builtin_bit_cast(short, h);
}
__device__ __forceinline__ float bs2f(unsigned short u) {
  unsigned v = ((unsigned)u) << 16;
  return __builtin_bit_cast(float, v);
}
// async global -> LDS, 16B per lane. LDS dest is wave-uniform base + lane*16;
// global src is per-lane.
__device__ __forceinline__ void gload_lds16(const void* g, void* l) {
  __builtin_amdgcn_global_load_lds((const __attribute__((address_space(1))) void*)g,
                                   (__attribute__((address_space(3))) void*)l, 16, 0, 0);
}

// ---------------- pack W0^T, Wm^T to bf16 [n][k] ----------------
__global__ void k_pack(const float* __restrict__ W0, const float* __restrict__ Wm,
                       short* __restrict__ W0T, short* __restrict__ WmT) {
  int i = blockIdx.x * blockDim.x + threadIdx.x;
  if (i < F_INN * HID) {
    int n = i / F_INN, k = i % F_INN;
    W0T[i] = f2bs(W0[k * HID + n]);
  } else if (i < F_INN * HID + 3 * HID * HID) {
    int j = i - F_INN * HID;
    int l = j / (HID * HID), rem = j % (HID * HID);
    int n = rem / HID, k = rem % HID;
    WmT[j] = f2bs(Wm[(l * HID + k) * HID + n]);
  }
}

__global__ void k_zero(float* p, int n) {
  int i = blockIdx.x * blockDim.x + threadIdx.x;
  if (i < n) p[i] = 0.0f;
}

// ---------------- CSR build ----------------
__global__ void k_init_deg(int* fill) {
  int i = blockIdx.x * blockDim.x + threadIdx.x;
  if (i < N_NODES) fill[i] = 1;  // self-loop
}

__global__ void k_count(const int* __restrict__ dst, int* fill) {
  int e = blockIdx.x * blockDim.x + threadIdx.x;
  if (e < N_EDGES) atomicAdd(&fill[clampn(dst[e])], 1);
}

__global__ void k_scan(int* fill, int* row_ptr) {
  __shared__ int sh[1024];
  int tid = threadIdx.x;
  int carry = 0;
  for (int base = 0; base < N_NODES; base += 1024) {
    int i = base + tid;
    int v = (i < N_NODES) ? fill[i] : 0;
    if (i < N_NODES) fill[i] = 0;
    sh[tid] = v;
    __syncthreads();
    for (int off = 1; off < 1024; off <<= 1) {
      int t = (tid >= off) ? sh[tid - off] : 0;
      __syncthreads();
      sh[tid] += t;
      __syncthreads();
    }
    if (i < N_NODES) row_ptr[i] = carry + sh[tid] - v;
    int tot = sh[1023];
    __syncthreads();
    carry += tot;
  }
  if (tid == 0) row_ptr[N_NODES] = carry;
}

__global__ void k_place(const int* __restrict__ src, const int* __restrict__ dst,
                        const int* __restrict__ row_ptr, int* fill, int* csr_src) {
  int id = blockIdx.x * blockDim.x + threadIdx.x;
  if (id >= ETOT) return;
  int s, d;
  if (id < N_EDGES) { s = clampn(src[id]); d = clampn(dst[id]); }
  else { s = id - N_EDGES; d = s; }
  int p = atomicAdd(&fill[d], 1);
  csr_src[row_ptr[d] + p] = s;
}

// ---------------- MFMA GEMM: LDS-staged B, phase pipeline ----------------
// T3 minimum-2-phase structure: per 64-wide K phase,
//   { stage B(p+1) via global_load_lds + load A(p+1) to regs;
//     ds_read 16 frags + 16 MFMA on phase p; __syncthreads(); }
// B is staged in FRAGMENT ORDER: chunk ci=(t*2+kk), lane-linear 16B slots, so
// every ds_read_b128 is lane-contiguous (conflict-free, no swizzle). The
// barrier pins the A prefetch (loads can't be sunk across s_barrier).
// Block = 4 waves x 16 rows = 64 rows. Tail rows masked (no early return:
// all waves must reach the barriers).
template <int K, bool BN>
__global__ __launch_bounds__(256, 2)
void k_gemm_mfma(const float* __restrict__ X, const short* __restrict__ BT,
                 const float* __restrict__ scale, const float* __restrict__ shift,
                 const float* __restrict__ a_s, const float* __restrict__ a_d,
                 short* __restrict__ hb, float* __restrict__ asrc,
                 float* __restrict__ adst) {
  constexpr int NP = K / 64;
  __shared__ short sB[2][8192];   // 2 x 16KB: [ci=(t*2+kk)][lane][8 bf16]
  int tid = threadIdx.x;
  int w = tid >> 6, lane = tid & 63;
  int m = lane & 15, q = lane >> 4;
  int row0 = blockIdx.x * 64 + w * 16;
  int rowm = row0 + m;
  int rowc = (rowm < N_NODES) ? rowm : 0;   // clamp OOB rows (tail block)
  const float* xbase = X + (size_t)rowc * K + q * 8;
  // B-staging global source: chunk ci -> lane reads BT[t*16+m][p64+kk*32+q*8]
  const short* gb = BT + (size_t)m * K + q * 8;

  f32x4 acc[8];
#pragma unroll
  for (int t = 0; t < 8; ++t) acc[t] = (f32x4){0.f, 0.f, 0.f, 0.f};
  float xr[2][16];

  // prologue: stage phase 0 + load A phase 0
#pragma unroll
  for (int c = 0; c < 4; ++c) {
    int ci = w * 4 + c;
    int t = ci >> 1, kk = ci & 1;
    gload_lds16(gb + (size_t)t * 16 * K + kk * 32, &sB[0][ci * 512]);
  }
  *(float4*)(&xr[0][0])  = *(const float4*)(xbase);
  *(float4*)(&xr[0][4])  = *(const float4*)(xbase + 4);
  *(float4*)(&xr[0][8])  = *(const float4*)(xbase + 32);
  *(float4*)(&xr[0][12]) = *(const float4*)(xbase + 36);
  __syncthreads();

#pragma unroll
  for (int p = 0; p < NP; ++p) {
    const int cur = p & 1;
    if (p + 1 < NP) {
      const int nxt = cur ^ 1;
      const int p64 = (p + 1) * 64;
#pragma unroll
      for (int c = 0; c < 4; ++c) {
        int ci = w * 4 + c;
        int t = ci >> 1, kk = ci & 1;
        gload_lds16(gb + (size_t)t * 16 * K + p64 + kk * 32, &sB[nxt][ci * 512]);
      }
      *(float4*)(&xr[nxt][0])  = *(const float4*)(xbase + p64);
      *(float4*)(&xr[nxt][4])  = *(const float4*)(xbase + p64 + 4);
      *(float4*)(&xr[nxt][8])  = *(const float4*)(xbase + p64 + 32);
      *(float4*)(&xr[nxt][12]) = *(const float4*)(xbase + p64 + 36);
    }
    const char* sbb = (const char*)&sB[cur][0] + ((size_t)lane << 4);
#pragma unroll
    for (int kk = 0; kk < 2; ++kk) {
      float xv[8];
#pragma unroll
      for (int j = 0; j < 8; ++j) xv[j] = xr[cur][kk * 8 + j];
      if (BN) {
        int kb = p * 64 + kk * 32 + q * 8;
        float sc[8], sf[8];
        *(float4*)(sc)     = *(const float4*)(scale + kb);
        *(float4*)(sc + 4) = *(const float4*)(scale + kb + 4);
        *(float4*)(sf)     = *(const float4*)(shift + kb);
        *(float4*)(sf + 4) = *(const float4*)(shift + kb + 4);
#pragma unroll
        for (int j = 0; j < 8; ++j) xv[j] = leaky(xv[j] * sc[j] + sf[j], 0.1f);
      }
      bf16x8 a;
#pragma unroll
      for (int j = 0; j < 8; ++j) a[j] = f2bs(xv[j]);
#pragma unroll
      for (int t = 0; t < 8; ++t) {
        bf16x8 b = *(const bf16x8*)(sbb + ((t * 2 + kk) << 10));
        acc[t] = __builtin_amdgcn_mfma_f32_16x16x32_bf16(a, b, acc[t], 0, 0, 0);
      }
    }
    if (p + 1 < NP) __syncthreads();
  }

  // epilogue: store h (bf16) + attention logits
  float sr[4] = {0.f, 0.f, 0.f, 0.f}, dr[4] = {0.f, 0.f, 0.f, 0.f};
  int rowq = row0 + q * 4;
#pragma unroll
  for (int t = 0; t < 8; ++t) {
    float av = a_s[t * 16 + m], dv = a_d[t * 16 + m];
#pragma unroll
    for (int r = 0; r < 4; ++r) {
      float c = acc[t][r];
      if (rowq + r < N_NODES)
        hb[(size_t)(rowq + r) * HID + t * 16 + m] = f2bs(c);
      sr[r] += c * av;
      dr[r] += c * dv;
    }
  }
#pragma unroll
  for (int r = 0; r < 4; ++r) {
#pragma unroll
    for (int off = 1; off < 16; off <<= 1) {
      sr[r] += __shfl_xor(sr[r], off);
      dr[r] += __shfl_xor(dr[r], off);
    }
  }
  if (m == 0) {
#pragma unroll
    for (int r = 0; r < 4; ++r) {
      if (rowq + r < N_NODES) {
        asrc[rowq + r] = sr[r];
        adst[rowq + r] = dr[r];
      }
    }
  }
}

// ---------------- GAT aggregation (H=128): one wave per node ----------------
// Gather phase: 4 edges in parallel (16 lanes x 16B = one 256B h-row each),
// 2 rounds in flight -> serial depth ~deg/8. Cross-edge-slot reduce via
// shfl_xor(16/32). Slots j >= cnt carry ex=0 (safe row 0 load).
__device__ __forceinline__ void acc8(float* a, float e, uint4 v) {
  a[0] += e * bs2f((unsigned short)(v.x & 0xffffu));
  a[1] += e * bs2f((unsigned short)(v.x >> 16));
  a[2] += e * bs2f((unsigned short)(v.y & 0xffffu));
  a[3] += e * bs2f((unsigned short)(v.y >> 16));
  a[4] += e * bs2f((unsigned short)(v.z & 0xffffu));
  a[5] += e * bs2f((unsigned short)(v.z >> 16));
  a[6] += e * bs2f((unsigned short)(v.w & 0xffffu));
  a[7] += e * bs2f((unsigned short)(v.w >> 16));
}

__global__ void k_agg128(const unsigned short* __restrict__ h, const float* __restrict__ asrc,
                         const float* __restrict__ adst, const int* __restrict__ row_ptr,
                         const int* __restrict__ csr_src, const float* __restrict__ bias,
                         const float* __restrict__ hres, const float* __restrict__ scale,
                         const float* __restrict__ shift, float* __restrict__ out) {
  __shared__ int   lds_ss[4][64];
  __shared__ float lds_ex[4][64];
  int wid = (blockIdx.x * blockDim.x + threadIdx.x) >> 6;
  int lane = threadIdx.x & 63;
  int w = (threadIdx.x >> 6) & 3;   // wave slot in block
  if (wid >= N_NODES) return;
  int beg = row_ptr[wid], end = row_ptr[wid + 1];
  float adsti = adst[wid];
  // pass A: lane-parallel max + butterfly reduce
  float mx = -1e30f;
  for (int cb = beg; cb < end; cb += 64) {
    int e = cb + lane;
    if (e < end) {
      int s = clampn(csr_src[e]);
      mx = fmaxf(mx, leaky(asrc[s] + adsti, 0.2f));
    }
  }
#pragma unroll
  for (int off = 1; off < 64; off <<= 1) mx = fmaxf(mx, __shfl_xor(mx, off));
  // pass B: lane-parallel exp -> LDS stage -> 4-edges-wide gather
  int g = lane & 15;    // 16-lane group position (covers cols g*8 .. g*8+7)
  int es = lane >> 4;   // edge slot 0..3
  float z = 0.f;
  float a[8];
#pragma unroll
  for (int k = 0; k < 8; ++k) a[k] = 0.f;
  for (int cb = beg; cb < end; cb += 64) {
    int cnt = min(64, end - cb);
    int sl = 0;
    float ex = 0.f;
    if (lane < cnt) {
      sl = clampn(csr_src[cb + lane]);
      ex = __expf(leaky(asrc[sl] + adsti, 0.2f) - mx);
    }
    lds_ss[w][lane] = sl;
    lds_ex[w][lane] = ex;
    __builtin_amdgcn_wave_barrier();   // pin LDS write before reads (wave-private region)
    float zp = ex;
#pragma unroll
    for (int off = 1; off < 64; off <<= 1) zp += __shfl_xor(zp, off);
    z += zp;
    for (int jb = 0; jb < cnt; jb += 8) {
      int j0 = jb + es, j1 = jb + 4 + es;      // j1 <= 63 always (jb <= 56)
      int s0 = lds_ss[w][j0]; float e0 = lds_ex[w][j0];
      int s1 = lds_ss[w][j1]; float e1 = lds_ex[w][j1];
      uint4 v0 = *(const uint4*)(h + (size_t)s0 * HID + g * 8);
      uint4 v1 = *(const uint4*)(h + (size_t)s1 * HID + g * 8);
      acc8(a, e0, v0);
      acc8(a, e1, v1);
    }
    __builtin_amdgcn_wave_barrier();   // keep next chunk's writes after these reads
  }
  // combine the 4 edge slots (each holds a full 128-col partial)
#pragma unroll
  for (int k = 0; k < 8; ++k) {
    a[k] += __shfl_xor(a[k], 16);
    a[k] += __shfl_xor(a[k], 32);
  }
  float inv = (z > 0.0f) ? 1.0f / z : 0.0f;
  if (lane < 16) {
    int c0 = g * 8;
    float hr[8];
    if (scale) {
      *(float4*)(hr)     = *(const float4*)(hres + (size_t)wid * HID + c0);
      *(float4*)(hr + 4) = *(const float4*)(hres + (size_t)wid * HID + c0 + 4);
    }
    float o[8];
#pragma unroll
    for (int k = 0; k < 8; ++k) {
      o[k] = a[k] * inv + bias[c0 + k];
      if (scale) o[k] += leaky(hr[k] * scale[c0 + k] + shift[c0 + k], 0.1f);
    }
    *(float4*)(out + (size_t)wid * HID + c0)     = *(float4*)(o);
    *(float4*)(out + (size_t)wid * HID + c0 + 4) = *(float4*)(o + 4);
  }
}

// ---------------- BatchNorm stats ----------------
__global__ void k_bn_stats(const float* __restrict__ h, float* bnsum, float* bnsumsq) {
  int f = threadIdx.x;  // 128
  int r0 = blockIdx.x * 128;
  int r1 = min(r0 + 128, N_NODES);
  float s = 0.0f, s2 = 0.0f;
#pragma unroll 8
  for (int r = r0; r < r1; ++r) {
    float v = h[(size_t)r * HID + f];
    s += v;
    s2 += v * v;
  }
  atomicAdd(&bnsum[f], s);
  atomicAdd(&bnsumsq[f], s2);
}

__global__ void k_bn_final(const float* __restrict__ bnsum, const float* __restrict__ bnsumsq,
                           const float* __restrict__ gamma, const float* __restrict__ beta,
                           float* bnscale, float* bnshift) {
  int f = threadIdx.x;
  float mu = bnsum[f] / (float)N_NODES;
  float var = bnsumsq[f] / (float)N_NODES - mu * mu;
  var = fmaxf(var, 0.0f);
  float rstd = rsqrtf(var + BN_EPS);
  float g = gamma[f];
  bnscale[f] = g * rstd;
  bnshift[f] = beta[f] - mu * g * rstd;
}

// ---------------- final layer GEMM (BN fused) + alpha logits ----------------
__global__ void k_final_gemm(const float* __restrict__ h, const float* __restrict__ scale,
                             const float* __restrict__ shift, const float* __restrict__ W4,
                             const float* __restrict__ a4s, const float* __restrict__ a4d,
                             float* __restrict__ h4, float* __restrict__ asrc,
                             float* __restrict__ adst) {
  int row = (blockIdx.x * blockDim.x + threadIdx.x) >> 6;
  int lane = threadIdx.x & 63;
  if (row >= N_NODES) return;
  float t0 = leaky(h[(size_t)row * HID + lane] * scale[lane] + shift[lane], 0.1f);
  float t1 = leaky(h[(size_t)row * HID + 64 + lane] * scale[64 + lane] + shift[64 + lane], 0.1f);
  float myv = 0.0f, s = 0.0f, d = 0.0f;
#pragma unroll
  for (int c = 0; c < N_CLS; ++c) {
    float p = t0 * W4[lane * N_CLS + c] + t1 * W4[(lane + 64) * N_CLS + c];
#pragma unroll
    for (int m = 32; m; m >>= 1) p += __shfl_xor(p, m);
    s += p * a4s[c];
    d += p * a4d[c];
    if (lane == c) myv = p;
  }
  if (lane < N_CLS) h4[(size_t)row * N_CLS + lane] = myv;
  if (lane == 0) { asrc[row] = s; adst[row] = d; }
}

// ---------------- final aggregation (C=9) -> fp32 output ----------------
__global__ void k_final_agg(const float* __restrict__ h4, const float* __restrict__ asrc,
                            const float* __restrict__ adst, const int* __restrict__ row_ptr,
                            const int* __restrict__ csr_src, const float* __restrict__ b4,
                            float* __restrict__ out) {
  int wid = (blockIdx.x * blockDim.x + threadIdx.x) >> 6;
  int lane = threadIdx.x & 63;
  if (wid >= N_NODES) return;
  int beg = row_ptr[wid], end = row_ptr[wid + 1];
  float adsti = adst[wid];
  float mx = -1e30f;
  int e = beg;
  for (; e + 4 <= end; e += 4) {
    int s0 = clampn(csr_src[e]),     s1 = clampn(csr_src[e + 1]);
    int s2 = clampn(csr_src[e + 2]), s3 = clampn(csr_src[e + 3]);
    float v0 = leaky(asrc[s0] + adsti, 0.2f);
    float v1 = leaky(asrc[s1] + adsti, 0.2f);
    float v2 = leaky(asrc[s2] + adsti, 0.2f);
    float v3 = leaky(asrc[s3] + adsti, 0.2f);
    mx = fmaxf(mx, fmaxf(fmaxf(v0, v1), fmaxf(v2, v3)));
  }
  for (; e < end; ++e) {
    int s = clampn(csr_src[e]);
    mx = fmaxf(mx, leaky(asrc[s] + adsti, 0.2f));
  }
  float z = 0.0f, a = 0.0f;
  e = beg;
  for (; e + 4 <= end; e += 4) {
    int s0 = clampn(csr_src[e]),     s1 = clampn(csr_src[e + 1]);
    int s2 = clampn(csr_src[e + 2]), s3 = clampn(csr_src[e + 3]);
    float ex0 = __expf(leaky(asrc[s0] + adsti, 0.2f) - mx);
    float ex1 = __expf(leaky(asrc[s1] + adsti, 0.2f) - mx);
    float ex2 = __expf(leaky(asrc[s2] + adsti, 0.2f) - mx);
    float ex3 = __expf(leaky(asrc[s3] + adsti, 0.2f) - mx);
    z += (ex0 + ex1) + (ex2 + ex3);
    if (lane < N_CLS) {
      float h0 = h4[(size_t)s0 * N_CLS + lane];
      float h1 = h4[(size_t)s1 * N_CLS + lane];
      float h2 = h4[(size_t)s2 * N_CLS + lane];
      float h3 = h4[(size_t)s3 * N_CLS + lane];
      a += ex0 * h0 + ex1 * h1 + ex2 * h2 + ex3 * h3;
    }
  }
  for (; e < end; ++e) {
    int s = clampn(csr_src[e]);
    float ex = __expf(leaky(asrc[s] + adsti, 0.2f) - mx);
    z += ex;
    if (lane < N_CLS) a += ex * h4[(size_t)s * N_CLS + lane];
  }
  if (lane < N_CLS) {
    float o = (z > 0.0f) ? a / z : 0.0f;
    o = leaky(o + b4[lane], 0.1f);
    out[(size_t)wid * N_CLS + lane] = o;
  }
}

extern "C" void kernel_launch(void* const* d_in, const int* in_sizes, int n_in,
                              void* d_out, int out_size, void* d_ws, size_t ws_size,
                              hipStream_t stream) {
  const float* x   = (const float*)d_in[0];
  const int*   ei  = (const int*)d_in[1];
  const int*   src = ei;
  const int*   dst = ei + N_EDGES;
  const float* W0  = (const float*)d_in[4];
  const float* a0s = (const float*)d_in[5];
  const float* a0d = (const float*)d_in[6];
  const float* b0  = (const float*)d_in[7];
  const float* Wm  = (const float*)d_in[8];
  const float* ams = (const float*)d_in[9];
  const float* amd = (const float*)d_in[10];
  const float* bm  = (const float*)d_in[11];
  const float* W4  = (const float*)d_in[12];
  const float* a4s = (const float*)d_in[13];
  const float* a4d = (const float*)d_in[14];
  const float* b4  = (const float*)d_in[15];
  const float* gam = (const float*)d_in[16];
  const float* bet = (const float*)d_in[17];
  float* out = (float*)d_out;

  // ---- workspace layout (~45 MB) ----
  int* row_ptr   = (int*)d_ws;                    // 50001 (pad 50004)
  int* fill      = row_ptr + 50004;               // N
  int* csr_src   = fill + N_NODES;                // ETOT
  short* W0T     = (short*)(csr_src + ETOT);      // 98304
  short* WmT     = W0T + F_INN * HID;             // 49152
  short* bufA    = WmT + 3 * HID * HID;           // N*128 bf16 (pre-agg h)
  float* asrc    = (float*)(bufA + (size_t)N_NODES * HID);  // N
  float* adst    = asrc + N_NODES;                // N
  float* bnsum   = adst + N_NODES;                // 128
  float* bnsumsq = bnsum + HID;                   // 128
  float* bnscale = bnsumsq + HID;                 // 128
  float* bnshift = bnscale + HID;                 // 128
  float* h4      = bnshift + HID;                 // N*9
  float* bufB    = h4 + (size_t)N_NODES * N_CLS;  // N*128 fp32 (running h)

  const int B256 = 256;
  int gN    = (N_NODES + B256 - 1) / B256;
  int gE    = (N_EDGES + B256 - 1) / B256;
  int gET   = (ETOT + B256 - 1) / B256;
  int gWav  = (N_NODES + 3) / 4;
  int gMfma = (N_NODES + 63) / 64;   // 64 rows per 256-thread block
  int gBN   = (N_NODES + 127) / 128;
  int gPack = (F_INN * HID + 3 * HID * HID + B256 - 1) / B256;

  // ---- pack weights + CSR ----
  k_pack<<<gPack, B256, 0, stream>>>(W0, Wm, W0T, WmT);
  k_init_deg<<<gN, B256, 0, stream>>>(fill);
  k_count<<<gE, B256, 0, stream>>>(dst, fill);
  k_scan<<<1, 1024, 0, stream>>>(fill, row_ptr);
  k_place<<<gET, B256, 0, stream>>>(src, dst, row_ptr, fill, csr_src);

  // ---- layer 0: h = GAT(x, W0, a0) + b0 -> bufB ----
  k_gemm_mfma<F_INN, false><<<gMfma, B256, 0, stream>>>(x, W0T, nullptr, nullptr,
                                                        a0s, a0d, bufA, asrc, adst);
  k_agg128<<<gWav, B256, 0, stream>>>((const unsigned short*)bufA, asrc, adst, row_ptr,
                                      csr_src, b0, nullptr, nullptr, nullptr, bufB);

  // ---- mid layers: t = leaky(bn(h),0.1) fused; h = GAT(t) + t ----
  for (int i = 0; i < 3; ++i) {
    k_zero<<<1, 256, 0, stream>>>(bnsum, 2 * HID);
    k_bn_stats<<<gBN, HID, 0, stream>>>(bufB, bnsum, bnsumsq);
    k_bn_final<<<1, HID, 0, stream>>>(bnsum, bnsumsq, gam + i * HID, bet + i * HID,
                                      bnscale, bnshift);
    k_gemm_mfma<HID, true><<<gMfma, B256, 0, stream>>>(bufB, WmT + i * HID * HID,
                                                       bnscale, bnshift,
                                                       ams + i * HID, amd + i * HID,
                                                       bufA, asrc, adst);
    k_agg128<<<gWav, B256, 0, stream>>>((const unsigned short*)bufA, asrc, adst, row_ptr,
                                        csr_src, bm + i * HID, bufB, bnscale, bnshift, bufB);
  }

  // ---- final: t = leaky(bn(h),0.1); out = leaky(GAT(t, W4), 0.1) ----
  k_zero<<<1, 256, 0, stream>>>(bnsum, 2 * HID);
  k_bn_stats<<<gBN, HID, 0, stream>>>(bufB, bnsum, bnsumsq);
  k_bn_final<<<1, HID, 0, stream>>>(bnsum, bnsumsq, gam + 3 * HID, bet + 3 * HID,
                                    bnscale, bnshift);
  k_final_gemm<<<gWav, B256, 0, stream>>>(bufB, bnscale, bnshift, W4, a4s, a4d,
                                          h4, asrc, adst);
  k_final_agg<<<gWav, B256, 0, stream>>>(h4, asrc, adst, row_ptr, csr_src, b4, out);
}

// Round 3
// 950.918 us; speedup vs baseline: 1.1360x; 1.0396x over previous
//
#include <hip/hip_runtime.h>
#include <hip/hip_bf16.h>

#define N_NODES 50000
#define N_EDGES 800000
#define F_INN   768
#define HID     128
#define N_CLS   9
#define ETOT    (N_EDGES + N_NODES)
#define BN_EPS  1e-5f

typedef __hip_bfloat16 bf16;
typedef __attribute__((ext_vector_type(8))) short bf16x8;
typedef __attribute__((ext_vector_type(4))) float f32x4;

__device__ __forceinline__ float leaky(float v, float s) { return v >= 0.0f ? v : s * v; }
__device__ __forceinline__ int clampn(int s) {
  return ((unsigned)s < (unsigned)N_NODES) ? s : 0;
}
__device__ __forceinline__ short f2bs(float f) {
  bf16 h = __float2bfloat16(f);
  return __builtin_bit_cast(short, h);
}
__device__ __forceinline__ float bs2f(unsigned short u) {
  unsigned v = ((unsigned)u) << 16;
  return __builtin_bit_cast(float, v);
}
// async global -> LDS, 16B per lane. LDS dest is wave-uniform base + lane*16;
// global src is per-lane.
__device__ __forceinline__ void gload_lds16(const void* g, void* l) {
  __builtin_amdgcn_global_load_lds((const __attribute__((address_space(1))) void*)g,
                                   (__attribute__((address_space(3))) void*)l, 16, 0, 0);
}

// ---------------- pack W0^T, Wm^T to bf16 [n][k] ----------------
__global__ void k_pack(const float* __restrict__ W0, const float* __restrict__ Wm,
                       short* __restrict__ W0T, short* __restrict__ WmT) {
  int i = blockIdx.x * blockDim.x + threadIdx.x;
  if (i < F_INN * HID) {
    int n = i / F_INN, k = i % F_INN;
    W0T[i] = f2bs(W0[k * HID + n]);
  } else if (i < F_INN * HID + 3 * HID * HID) {
    int j = i - F_INN * HID;
    int l = j / (HID * HID), rem = j % (HID * HID);
    int n = rem / HID, k = rem % HID;
    WmT[j] = f2bs(Wm[(l * HID + k) * HID + n]);
  }
}

__global__ void k_zero(float* p, int n) {
  int i = blockIdx.x * blockDim.x + threadIdx.x;
  if (i < n) p[i] = 0.0f;
}

// ---------------- CSR build ----------------
__global__ void k_init_deg(int* fill) {
  int i = blockIdx.x * blockDim.x + threadIdx.x;
  if (i < N_NODES) fill[i] = 1;  // self-loop
}

__global__ void k_count(const int* __restrict__ dst, int* fill) {
  int e = blockIdx.x * blockDim.x + threadIdx.x;
  if (e < N_EDGES) atomicAdd(&fill[clampn(dst[e])], 1);
}

// shuffle-based scan: 3 barriers per 1024-chunk (was ~20 -> ~40us on one CU)
__global__ void k_scan(int* fill, int* row_ptr) {
  __shared__ int wsum[16], wpre[16];
  int tid = threadIdx.x, lane = tid & 63, wv = tid >> 6;
  int carry = 0;
  for (int base = 0; base < N_NODES; base += 1024) {
    int i = base + tid;
    int v = (i < N_NODES) ? fill[i] : 0;
    if (i < N_NODES) fill[i] = 0;
    int sc = v;
#pragma unroll
    for (int off = 1; off < 64; off <<= 1) {
      int t = __shfl_up(sc, off);
      if (lane >= off) sc += t;
    }
    if (lane == 63) wsum[wv] = sc;
    __syncthreads();
    if (tid < 16) {
      int s = wsum[tid];
#pragma unroll
      for (int off = 1; off < 16; off <<= 1) {
        int t = __shfl_up(s, off);
        if (tid >= off) s += t;
      }
      wpre[tid] = s;
    }
    __syncthreads();
    int woff = wv ? wpre[wv - 1] : 0;
    if (i < N_NODES) row_ptr[i] = carry + woff + sc - v;
    carry += wpre[15];
    __syncthreads();
  }
  if (tid == 0) row_ptr[N_NODES] = carry;
}

__global__ void k_place(const int* __restrict__ src, const int* __restrict__ dst,
                        const int* __restrict__ row_ptr, int* fill, int* csr_src) {
  int id = blockIdx.x * blockDim.x + threadIdx.x;
  if (id >= ETOT) return;
  int s, d;
  if (id < N_EDGES) { s = clampn(src[id]); d = clampn(dst[id]); }
  else { s = id - N_EDGES; d = s; }
  int p = atomicAdd(&fill[d], 1);
  csr_src[row_ptr[d] + p] = s;
}

// ---------------- MFMA GEMM: counted-vmcnt 4-buffer ring pipeline ----------------
// T3+T4: prefetch depth 2, exactly 8 VMEM per phase (4 global_load_lds for B +
// 4 float4 X loads into a static-indexed VGPR ring). Inline-asm
// s_waitcnt vmcnt(16) drains only phase p (p+1, p+2 stay in flight across the
// raw s_barrier) -- never vmcnt(0) in the main loop. The asm "memory" fences
// pin each phase's loads into its slot so the counts stay valid.
// NB=4 ring: writer(p+2) vs oldest reader(p-1) differ by 3 mod 4 -> race-free
// with ONE barrier per phase. BN scale/shift hoisted to regs before the loop
// (an in-loop load would force a deep vmcnt drain).
template <int K, bool BN>
__global__ __launch_bounds__(256, 2)
void k_gemm_mfma(const float* __restrict__ X, const short* __restrict__ BT,
                 const float* __restrict__ scale, const float* __restrict__ shift,
                 const float* __restrict__ a_s, const float* __restrict__ a_d,
                 short* __restrict__ hb, float* __restrict__ asrc,
                 float* __restrict__ adst) {
  constexpr int NP = K / 64;
  constexpr int NB = 4;
  __shared__ short sB[NB][8192];   // 4 x 16KB: [ci=(t*2+kk)][lane][8 bf16]
  int tid = threadIdx.x;
  int w = tid >> 6, lane = tid & 63;
  int m = lane & 15, q = lane >> 4;
  int row0 = blockIdx.x * 64 + w * 16;
  int rowm = row0 + m;
  int rowc = (rowm < N_NODES) ? rowm : 0;   // clamp OOB rows (tail block)
  const float* xbase = X + (size_t)rowc * K + q * 8;
  const short* gb = BT + (size_t)m * K + q * 8;

  f32x4 acc[8];
#pragma unroll
  for (int t = 0; t < 8; ++t) acc[t] = (f32x4){0.f, 0.f, 0.f, 0.f};
  float4 xr[NB][4];

  // BN scale/shift: hoist the per-lane slices into registers (K<=128 path).
  float scf[K / 32][8], sff[K / 32][8];
  if (BN) {
#pragma unroll
    for (int c = 0; c < K / 32; ++c) {
      int kb = c * 32 + q * 8;
      *(float4*)(&scf[c][0]) = *(const float4*)(scale + kb);
      *(float4*)(&scf[c][4]) = *(const float4*)(scale + kb + 4);
      *(float4*)(&sff[c][0]) = *(const float4*)(shift + kb);
      *(float4*)(&sff[c][4]) = *(const float4*)(shift + kb + 4);
    }
  }

  // exactly 8 VMEM ops per call; all indices compile-time under full unroll
  auto issue = [&](int p) {
    const int buf = p & (NB - 1);
#pragma unroll
    for (int c = 0; c < 4; ++c) {
      int ci = w * 4 + c;
      int t = ci >> 1, kk = ci & 1;
      gload_lds16(gb + (size_t)t * 16 * K + p * 64 + kk * 32, &sB[buf][ci * 512]);
    }
    xr[buf][0] = *(const float4*)(xbase + p * 64);
    xr[buf][1] = *(const float4*)(xbase + p * 64 + 4);
    xr[buf][2] = *(const float4*)(xbase + p * 64 + 32);
    xr[buf][3] = *(const float4*)(xbase + p * 64 + 36);
  };

  issue(0);
  if (NP > 1) issue(1);

#pragma unroll
  for (int p = 0; p < NP; ++p) {
    if (p + 2 < NP) issue(p + 2);
    // counted waits: 8 VMEM per phase in flight; drain exactly phase p
    if (p + 2 < NP)      asm volatile("s_waitcnt vmcnt(16)" ::: "memory");
    else if (p + 1 < NP) asm volatile("s_waitcnt vmcnt(8)" ::: "memory");
    else                 asm volatile("s_waitcnt vmcnt(0)" ::: "memory");
    __builtin_amdgcn_s_barrier();

    const int cur = p & (NB - 1);
    const char* sbb = (const char*)&sB[cur][0] + ((size_t)lane << 4);
#pragma unroll
    for (int kk = 0; kk < 2; ++kk) {
      float xv[8];
      *(float4*)(xv)     = xr[cur][kk * 2];
      *(float4*)(xv + 4) = xr[cur][kk * 2 + 1];
      if (BN) {
#pragma unroll
        for (int j = 0; j < 8; ++j)
          xv[j] = leaky(xv[j] * scf[p * 2 + kk][j] + sff[p * 2 + kk][j], 0.1f);
      }
      bf16x8 a;
#pragma unroll
      for (int j = 0; j < 8; ++j) a[j] = f2bs(xv[j]);
#pragma unroll
      for (int t = 0; t < 8; ++t) {
        bf16x8 b = *(const bf16x8*)(sbb + ((t * 2 + kk) << 10));
        acc[t] = __builtin_amdgcn_mfma_f32_16x16x32_bf16(a, b, acc[t], 0, 0, 0);
      }
    }
  }

  // epilogue: store h (bf16) + attention logits
  float sr[4] = {0.f, 0.f, 0.f, 0.f}, dr[4] = {0.f, 0.f, 0.f, 0.f};
  int rowq = row0 + q * 4;
#pragma unroll
  for (int t = 0; t < 8; ++t) {
    float av = a_s[t * 16 + m], dv = a_d[t * 16 + m];
#pragma unroll
    for (int r = 0; r < 4; ++r) {
      float c = acc[t][r];
      if (rowq + r < N_NODES)
        hb[(size_t)(rowq + r) * HID + t * 16 + m] = f2bs(c);
      sr[r] += c * av;
      dr[r] += c * dv;
    }
  }
#pragma unroll
  for (int r = 0; r < 4; ++r) {
#pragma unroll
    for (int off = 1; off < 16; off <<= 1) {
      sr[r] += __shfl_xor(sr[r], off);
      dr[r] += __shfl_xor(dr[r], off);
    }
  }
  if (m == 0) {
#pragma unroll
    for (int r = 0; r < 4; ++r) {
      if (rowq + r < N_NODES) {
        asrc[rowq + r] = sr[r];
        adst[rowq + r] = dr[r];
      }
    }
  }
}

// ---------------- GAT aggregation (H=128): one wave per node ----------------
// Gather phase: 4 edges in parallel (16 lanes x 16B = one 256B h-row each),
// 2 rounds in flight -> serial depth ~deg/8. Cross-edge-slot reduce via
// shfl_xor(16/32). Slots j >= cnt carry ex=0 (safe row 0 load).
__device__ __forceinline__ void acc8(float* a, float e, uint4 v) {
  a[0] += e * bs2f((unsigned short)(v.x & 0xffffu));
  a[1] += e * bs2f((unsigned short)(v.x >> 16));
  a[2] += e * bs2f((unsigned short)(v.y & 0xffffu));
  a[3] += e * bs2f((unsigned short)(v.y >> 16));
  a[4] += e * bs2f((unsigned short)(v.z & 0xffffu));
  a[5] += e * bs2f((unsigned short)(v.z >> 16));
  a[6] += e * bs2f((unsigned short)(v.w & 0xffffu));
  a[7] += e * bs2f((unsigned short)(v.w >> 16));
}

__global__ void k_agg128(const unsigned short* __restrict__ h, const float* __restrict__ asrc,
                         const float* __restrict__ adst, const int* __restrict__ row_ptr,
                         const int* __restrict__ csr_src, const float* __restrict__ bias,
                         const float* __restrict__ hres, const float* __restrict__ scale,
                         const float* __restrict__ shift, float* __restrict__ out) {
  __shared__ int   lds_ss[4][64];
  __shared__ float lds_ex[4][64];
  int wid = (blockIdx.x * blockDim.x + threadIdx.x) >> 6;
  int lane = threadIdx.x & 63;
  int w = (threadIdx.x >> 6) & 3;   // wave slot in block
  if (wid >= N_NODES) return;
  int beg = row_ptr[wid], end = row_ptr[wid + 1];
  float adsti = adst[wid];
  // pass A: lane-parallel max + butterfly reduce
  float mx = -1e30f;
  for (int cb = beg; cb < end; cb += 64) {
    int e = cb + lane;
    if (e < end) {
      int s = clampn(csr_src[e]);
      mx = fmaxf(mx, leaky(asrc[s] + adsti, 0.2f));
    }
  }
#pragma unroll
  for (int off = 1; off < 64; off <<= 1) mx = fmaxf(mx, __shfl_xor(mx, off));
  // pass B: lane-parallel exp -> LDS stage -> 4-edges-wide gather
  int g = lane & 15;    // 16-lane group position (covers cols g*8 .. g*8+7)
  int es = lane >> 4;   // edge slot 0..3
  float z = 0.f;
  float a[8];
#pragma unroll
  for (int k = 0; k < 8; ++k) a[k] = 0.f;
  for (int cb = beg; cb < end; cb += 64) {
    int cnt = min(64, end - cb);
    int sl = 0;
    float ex = 0.f;
    if (lane < cnt) {
      sl = clampn(csr_src[cb + lane]);
      ex = __expf(leaky(asrc[sl] + adsti, 0.2f) - mx);
    }
    lds_ss[w][lane] = sl;
    lds_ex[w][lane] = ex;
    __builtin_amdgcn_wave_barrier();   // pin LDS write before reads (wave-private region)
    float zp = ex;
#pragma unroll
    for (int off = 1; off < 64; off <<= 1) zp += __shfl_xor(zp, off);
    z += zp;
    for (int jb = 0; jb < cnt; jb += 8) {
      int j0 = jb + es, j1 = jb + 4 + es;      // j1 <= 63 always (jb <= 56)
      int s0 = lds_ss[w][j0]; float e0 = lds_ex[w][j0];
      int s1 = lds_ss[w][j1]; float e1 = lds_ex[w][j1];
      uint4 v0 = *(const uint4*)(h + (size_t)s0 * HID + g * 8);
      uint4 v1 = *(const uint4*)(h + (size_t)s1 * HID + g * 8);
      acc8(a, e0, v0);
      acc8(a, e1, v1);
    }
    __builtin_amdgcn_wave_barrier();   // keep next chunk's writes after these reads
  }
  // combine the 4 edge slots (each holds a full 128-col partial)
#pragma unroll
  for (int k = 0; k < 8; ++k) {
    a[k] += __shfl_xor(a[k], 16);
    a[k] += __shfl_xor(a[k], 32);
  }
  float inv = (z > 0.0f) ? 1.0f / z : 0.0f;
  if (lane < 16) {
    int c0 = g * 8;
    float hr[8];
    if (scale) {
      *(float4*)(hr)     = *(const float4*)(hres + (size_t)wid * HID + c0);
      *(float4*)(hr + 4) = *(const float4*)(hres + (size_t)wid * HID + c0 + 4);
    }
    float o[8];
#pragma unroll
    for (int k = 0; k < 8; ++k) {
      o[k] = a[k] * inv + bias[c0 + k];
      if (scale) o[k] += leaky(hr[k] * scale[c0 + k] + shift[c0 + k], 0.1f);
    }
    *(float4*)(out + (size_t)wid * HID + c0)     = *(float4*)(o);
    *(float4*)(out + (size_t)wid * HID + c0 + 4) = *(float4*)(o + 4);
  }
}

// ---------------- BatchNorm stats ----------------
__global__ void k_bn_stats(const float* __restrict__ h, float* bnsum, float* bnsumsq) {
  int f = threadIdx.x;  // 128
  int r0 = blockIdx.x * 128;
  int r1 = min(r0 + 128, N_NODES);
  float s = 0.0f, s2 = 0.0f;
#pragma unroll 8
  for (int r = r0; r < r1; ++r) {
    float v = h[(size_t)r * HID + f];
    s += v;
    s2 += v * v;
  }
  atomicAdd(&bnsum[f], s);
  atomicAdd(&bnsumsq[f], s2);
}

__global__ void k_bn_final(const float* __restrict__ bnsum, const float* __restrict__ bnsumsq,
                           const float* __restrict__ gamma, const float* __restrict__ beta,
                           float* bnscale, float* bnshift) {
  int f = threadIdx.x;
  float mu = bnsum[f] / (float)N_NODES;
  float var = bnsumsq[f] / (float)N_NODES - mu * mu;
  var = fmaxf(var, 0.0f);
  float rstd = rsqrtf(var + BN_EPS);
  float g = gamma[f];
  bnscale[f] = g * rstd;
  bnshift[f] = beta[f] - mu * g * rstd;
}

// ---------------- final layer GEMM (BN fused) + alpha logits ----------------
__global__ void k_final_gemm(const float* __restrict__ h, const float* __restrict__ scale,
                             const float* __restrict__ shift, const float* __restrict__ W4,
                             const float* __restrict__ a4s, const float* __restrict__ a4d,
                             float* __restrict__ h4, float* __restrict__ asrc,
                             float* __restrict__ adst) {
  int row = (blockIdx.x * blockDim.x + threadIdx.x) >> 6;
  int lane = threadIdx.x & 63;
  if (row >= N_NODES) return;
  float t0 = leaky(h[(size_t)row * HID + lane] * scale[lane] + shift[lane], 0.1f);
  float t1 = leaky(h[(size_t)row * HID + 64 + lane] * scale[64 + lane] + shift[64 + lane], 0.1f);
  float myv = 0.0f, s = 0.0f, d = 0.0f;
#pragma unroll
  for (int c = 0; c < N_CLS; ++c) {
    float p = t0 * W4[lane * N_CLS + c] + t1 * W4[(lane + 64) * N_CLS + c];
#pragma unroll
    for (int m = 32; m; m >>= 1) p += __shfl_xor(p, m);
    s += p * a4s[c];
    d += p * a4d[c];
    if (lane == c) myv = p;
  }
  if (lane < N_CLS) h4[(size_t)row * N_CLS + lane] = myv;
  if (lane == 0) { asrc[row] = s; adst[row] = d; }
}

// ---------------- final aggregation (C=9) -> fp32 output ----------------
__global__ void k_final_agg(const float* __restrict__ h4, const float* __restrict__ asrc,
                            const float* __restrict__ adst, const int* __restrict__ row_ptr,
                            const int* __restrict__ csr_src, const float* __restrict__ b4,
                            float* __restrict__ out) {
  int wid = (blockIdx.x * blockDim.x + threadIdx.x) >> 6;
  int lane = threadIdx.x & 63;
  if (wid >= N_NODES) return;
  int beg = row_ptr[wid], end = row_ptr[wid + 1];
  float adsti = adst[wid];
  float mx = -1e30f;
  int e = beg;
  for (; e + 4 <= end; e += 4) {
    int s0 = clampn(csr_src[e]),     s1 = clampn(csr_src[e + 1]);
    int s2 = clampn(csr_src[e + 2]), s3 = clampn(csr_src[e + 3]);
    float v0 = leaky(asrc[s0] + adsti, 0.2f);
    float v1 = leaky(asrc[s1] + adsti, 0.2f);
    float v2 = leaky(asrc[s2] + adsti, 0.2f);
    float v3 = leaky(asrc[s3] + adsti, 0.2f);
    mx = fmaxf(mx, fmaxf(fmaxf(v0, v1), fmaxf(v2, v3)));
  }
  for (; e < end; ++e) {
    int s = clampn(csr_src[e]);
    mx = fmaxf(mx, leaky(asrc[s] + adsti, 0.2f));
  }
  float z = 0.0f, a = 0.0f;
  e = beg;
  for (; e + 4 <= end; e += 4) {
    int s0 = clampn(csr_src[e]),     s1 = clampn(csr_src[e + 1]);
    int s2 = clampn(csr_src[e + 2]), s3 = clampn(csr_src[e + 3]);
    float ex0 = __expf(leaky(asrc[s0] + adsti, 0.2f) - mx);
    float ex1 = __expf(leaky(asrc[s1] + adsti, 0.2f) - mx);
    float ex2 = __expf(leaky(asrc[s2] + adsti, 0.2f) - mx);
    float ex3 = __expf(leaky(asrc[s3] + adsti, 0.2f) - mx);
    z += (ex0 + ex1) + (ex2 + ex3);
    if (lane < N_CLS) {
      float h0 = h4[(size_t)s0 * N_CLS + lane];
      float h1 = h4[(size_t)s1 * N_CLS + lane];
      float h2 = h4[(size_t)s2 * N_CLS + lane];
      float h3 = h4[(size_t)s3 * N_CLS + lane];
      a += ex0 * h0 + ex1 * h1 + ex2 * h2 + ex3 * h3;
    }
  }
  for (; e < end; ++e) {
    int s = clampn(csr_src[e]);
    float ex = __expf(leaky(asrc[s] + adsti, 0.2f) - mx);
    z += ex;
    if (lane < N_CLS) a += ex * h4[(size_t)s * N_CLS + lane];
  }
  if (lane < N_CLS) {
    float o = (z > 0.0f) ? a / z : 0.0f;
    o = leaky(o + b4[lane], 0.1f);
    out[(size_t)wid * N_CLS + lane] = o;
  }
}

extern "C" void kernel_launch(void* const* d_in, const int* in_sizes, int n_in,
                              void* d_out, int out_size, void* d_ws, size_t ws_size,
                              hipStream_t stream) {
  const float* x   = (const float*)d_in[0];
  const int*   ei  = (const int*)d_in[1];
  const int*   src = ei;
  const int*   dst = ei + N_EDGES;
  const float* W0  = (const float*)d_in[4];
  const float* a0s = (const float*)d_in[5];
  const float* a0d = (const float*)d_in[6];
  const float* b0  = (const float*)d_in[7];
  const float* Wm  = (const float*)d_in[8];
  const float* ams = (const float*)d_in[9];
  const float* amd = (const float*)d_in[10];
  const float* bm  = (const float*)d_in[11];
  const float* W4  = (const float*)d_in[12];
  const float* a4s = (const float*)d_in[13];
  const float* a4d = (const float*)d_in[14];
  const float* b4  = (const float*)d_in[15];
  const float* gam = (const float*)d_in[16];
  const float* bet = (const float*)d_in[17];
  float* out = (float*)d_out;

  // ---- workspace layout (~45 MB) ----
  int* row_ptr   = (int*)d_ws;                    // 50001 (pad 50004)
  int* fill      = row_ptr + 50004;               // N
  int* csr_src   = fill + N_NODES;                // ETOT
  short* W0T     = (short*)(csr_src + ETOT);      // 98304
  short* WmT     = W0T + F_INN * HID;             // 49152
  short* bufA    = WmT + 3 * HID * HID;           // N*128 bf16 (pre-agg h)
  float* asrc    = (float*)(bufA + (size_t)N_NODES * HID);  // N
  float* adst    = asrc + N_NODES;                // N
  float* bnsum   = adst + N_NODES;                // 128
  float* bnsumsq = bnsum + HID;                   // 128
  float* bnscale = bnsumsq + HID;                 // 128
  float* bnshift = bnscale + HID;                 // 128
  float* h4      = bnshift + HID;                 // N*9
  float* bufB    = h4 + (size_t)N_NODES * N_CLS;  // N*128 fp32 (running h)

  const int B256 = 256;
  int gN    = (N_NODES + B256 - 1) / B256;
  int gE    = (N_EDGES + B256 - 1) / B256;
  int gET   = (ETOT + B256 - 1) / B256;
  int gWav  = (N_NODES + 3) / 4;
  int gMfma = (N_NODES + 63) / 64;   // 64 rows per 256-thread block
  int gBN   = (N_NODES + 127) / 128;
  int gPack = (F_INN * HID + 3 * HID * HID + B256 - 1) / B256;

  // ---- pack weights + CSR ----
  k_pack<<<gPack, B256, 0, stream>>>(W0, Wm, W0T, WmT);
  k_init_deg<<<gN, B256, 0, stream>>>(fill);
  k_count<<<gE, B256, 0, stream>>>(dst, fill);
  k_scan<<<1, 1024, 0, stream>>>(fill, row_ptr);
  k_place<<<gET, B256, 0, stream>>>(src, dst, row_ptr, fill, csr_src);

  // ---- layer 0: h = GAT(x, W0, a0) + b0 -> bufB ----
  k_gemm_mfma<F_INN, false><<<gMfma, B256, 0, stream>>>(x, W0T, nullptr, nullptr,
                                                        a0s, a0d, bufA, asrc, adst);
  k_agg128<<<gWav, B256, 0, stream>>>((const unsigned short*)bufA, asrc, adst, row_ptr,
                                      csr_src, b0, nullptr, nullptr, nullptr, bufB);

  // ---- mid layers: t = leaky(bn(h),0.1) fused; h = GAT(t) + t ----
  for (int i = 0; i < 3; ++i) {
    k_zero<<<1, 256, 0, stream>>>(bnsum, 2 * HID);
    k_bn_stats<<<gBN, HID, 0, stream>>>(bufB, bnsum, bnsumsq);
    k_bn_final<<<1, HID, 0, stream>>>(bnsum, bnsumsq, gam + i * HID, bet + i * HID,
                                      bnscale, bnshift);
    k_gemm_mfma<HID, true><<<gMfma, B256, 0, stream>>>(bufB, WmT + i * HID * HID,
                                                       bnscale, bnshift,
                                                       ams + i * HID, amd + i * HID,
                                                       bufA, asrc, adst);
    k_agg128<<<gWav, B256, 0, stream>>>((const unsigned short*)bufA, asrc, adst, row_ptr,
                                        csr_src, bm + i * HID, bufB, bnscale, bnshift, bufB);
  }

  // ---- final: t = leaky(bn(h),0.1); out = leaky(GAT(t, W4), 0.1) ----
  k_zero<<<1, 256, 0, stream>>>(bnsum, 2 * HID);
  k_bn_stats<<<gBN, HID, 0, stream>>>(bufB, bnsum, bnsumsq);
  k_bn_final<<<1, HID, 0, stream>>>(bnsum, bnsumsq, gam + 3 * HID, bet + 3 * HID,
                                    bnscale, bnshift);
  k_final_gemm<<<gWav, B256, 0, stream>>>(bufB, bnscale, bnshift, W4, a4s, a4d,
                                          h4, asrc, adst);
  k_final_agg<<<gWav, B256, 0, stream>>>(h4, asrc, adst, row_ptr, csr_src, b4, out);
}

// Round 4
// 808.010 us; speedup vs baseline: 1.3369x; 1.1769x over previous
//
#include <hip/hip_runtime.h>
#include <hip/hip_bf16.h>

#define N_NODES 50000
#define N_EDGES 800000
#define F_INN   768
#define HID     128
#define N_CLS   9
#define ETOT    (N_EDGES + N_NODES)
#define BN_EPS  1e-5f
#define INV_N   (1.0f / (float)N_NODES)

typedef __hip_bfloat16 bf16;
typedef __attribute__((ext_vector_type(8))) short bf16x8;
typedef __attribute__((ext_vector_type(4))) float f32x4;

__device__ __forceinline__ float leaky(float v, float s) { return v >= 0.0f ? v : s * v; }
__device__ __forceinline__ int clampn(int s) {
  return ((unsigned)s < (unsigned)N_NODES) ? s : 0;
}
__device__ __forceinline__ short f2bs(float f) {
  bf16 h = __float2bfloat16(f);
  return __builtin_bit_cast(short, h);
}
__device__ __forceinline__ float bs2f(unsigned short u) {
  unsigned v = ((unsigned)u) << 16;
  return __builtin_bit_cast(float, v);
}
__device__ __forceinline__ void gload_lds16(const void* g, void* l) {
  __builtin_amdgcn_global_load_lds((const __attribute__((address_space(1))) void*)g,
                                   (__attribute__((address_space(3))) void*)l, 16, 0, 0);
}

// ---------------- pack W0^T, Wm^T to bf16 [n][k] ----------------
__global__ void k_pack(const float* __restrict__ W0, const float* __restrict__ Wm,
                       short* __restrict__ W0T, short* __restrict__ WmT) {
  int i = blockIdx.x * blockDim.x + threadIdx.x;
  if (i < F_INN * HID) {
    int n = i / F_INN, k = i % F_INN;
    W0T[i] = f2bs(W0[k * HID + n]);
  } else if (i < F_INN * HID + 3 * HID * HID) {
    int j = i - F_INN * HID;
    int l = j / (HID * HID), rem = j % (HID * HID);
    int n = rem / HID, k = rem % HID;
    WmT[j] = f2bs(Wm[(l * HID + k) * HID + n]);
  }
}

// ---------------- CSR build ----------------
__global__ void k_init_deg(int* fill) {
  int i = blockIdx.x * blockDim.x + threadIdx.x;
  if (i < N_NODES) fill[i] = 1;  // self-loop
}

__global__ void k_count(const int* __restrict__ dst, int* fill) {
  int e = blockIdx.x * blockDim.x + threadIdx.x;
  if (e < N_EDGES) atomicAdd(&fill[clampn(dst[e])], 1);
}

// shuffle-based scan: 3 barriers per 1024-chunk
__global__ void k_scan(int* fill, int* row_ptr) {
  __shared__ int wsum[16], wpre[16];
  int tid = threadIdx.x, lane = tid & 63, wv = tid >> 6;
  int carry = 0;
  for (int base = 0; base < N_NODES; base += 1024) {
    int i = base + tid;
    int v = (i < N_NODES) ? fill[i] : 0;
    if (i < N_NODES) fill[i] = 0;
    int sc = v;
#pragma unroll
    for (int off = 1; off < 64; off <<= 1) {
      int t = __shfl_up(sc, off);
      if (lane >= off) sc += t;
    }
    if (lane == 63) wsum[wv] = sc;
    __syncthreads();
    if (tid < 16) {
      int s = wsum[tid];
#pragma unroll
      for (int off = 1; off < 16; off <<= 1) {
        int t = __shfl_up(s, off);
        if (tid >= off) s += t;
      }
      wpre[tid] = s;
    }
    __syncthreads();
    int woff = wv ? wpre[wv - 1] : 0;
    if (i < N_NODES) row_ptr[i] = carry + woff + sc - v;
    carry += wpre[15];
    __syncthreads();
  }
  if (tid == 0) row_ptr[N_NODES] = carry;
}

__global__ void k_place(const int* __restrict__ src, const int* __restrict__ dst,
                        const int* __restrict__ row_ptr, int* fill, int* csr_src) {
  int id = blockIdx.x * blockDim.x + threadIdx.x;
  if (id >= ETOT) return;
  int s, d;
  if (id < N_EDGES) { s = clampn(src[id]); d = clampn(dst[id]); }
  else { s = id - N_EDGES; d = s; }
  int p = atomicAdd(&fill[d], 1);
  csr_src[row_ptr[d] + p] = s;
}

// ---------------- MFMA GEMM: X-in-LDS-once, B-in-registers ----------------
// Global latency is paid ONCE per wave (stage X 16xK to LDS + B chunk loads),
// not once per K-phase. Block = 8 waves x 16 rows; wave w owns cols w*16..+15
// with its B fragments in regs (double-buffered 16-reg chunks of 4 MFMA steps).
// X staged via global_load_lds with XOR-swizzled SOURCE + linear dest (rule:
// swizzle both sides or neither); reads apply the same XOR -> conflict-free.
// BN scale/shift computed in-kernel from the stats sums (k_bn_final fused).
// N_NODES = 3125 * 16 exactly: no tail handling needed.
template <int K, bool BN>
__global__ __launch_bounds__(512, 5)
void k_gemm_mfma(const float* __restrict__ X, const short* __restrict__ BT,
                 const float* __restrict__ stats, const float* __restrict__ gamma,
                 const float* __restrict__ beta,
                 const float* __restrict__ a_s, const float* __restrict__ a_d,
                 short* __restrict__ hb, float* __restrict__ asrc,
                 float* __restrict__ adst) {
  constexpr int NS = K / 32;        // MFMA steps (24 or 4)
  constexpr int SPC = 4;            // steps per B chunk
  constexpr int CH = NS / SPC;      // chunks (6 or 1)
  constexpr int ROWB = K * 4;       // X row bytes
  constexpr int XB = 16 * ROWB;     // staged X bytes (49152 or 8192)
  __shared__ float4 xs4[XB / 16];
  __shared__ float psA[8][16], psD[8][16];
  __shared__ float scs[HID], sfs[HID];
  char* xs = (char*)xs4;

  int tid = threadIdx.x;
  int wid = tid >> 6, lane = tid & 63;
  int m = lane & 15, q = lane >> 4;
  int row0 = blockIdx.x * 16;
  int col0 = wid * 16;

  const short* bbase = BT + (size_t)(col0 + m) * K + q * 8;
  f32x4 acc = (f32x4){0.f, 0.f, 0.f, 0.f};
  bf16x8 bb0[SPC], bb1[SPC];

  auto loadC = [&](bf16x8* dst, int c) {
#pragma unroll
    for (int i = 0; i < SPC; ++i)
      dst[i] = *(const bf16x8*)(bbase + (size_t)(c * SPC + i) * 32);
  };
  auto computeC = [&](const bf16x8* bw, int c) {
#pragma unroll
    for (int i = 0; i < SPC; ++i) {
      int s = c * SPC + i;
      int kb = s * 128 + q * 32;
      int sw = (m & 7) << 4;
      float4 x0 = *(const float4*)(xs + m * ROWB + (kb ^ sw));
      float4 x1 = *(const float4*)(xs + m * ROWB + ((kb + 16) ^ sw));
      float xv[8] = {x0.x, x0.y, x0.z, x0.w, x1.x, x1.y, x1.z, x1.w};
      if (BN) {
        int k0 = s * 32 + q * 8;
#pragma unroll
        for (int j = 0; j < 8; ++j) xv[j] = leaky(xv[j] * scs[k0 + j] + sfs[k0 + j], 0.1f);
      }
      bf16x8 a;
#pragma unroll
      for (int j = 0; j < 8; ++j) a[j] = f2bs(xv[j]);
      acc = __builtin_amdgcn_mfma_f32_16x16x32_bf16(a, bw[i], acc, 0, 0, 0);
    }
  };

  // BN: fold bn_final into the GEMM (scale/shift from sums, once per block)
  if (BN && tid < HID) {
    float mu = stats[tid] * INV_N;
    float var = fmaxf(stats[HID + tid] * INV_N - mu * mu, 0.0f);
    float rs = rsqrtf(var + BN_EPS);
    float g = gamma[tid];
    scs[tid] = g * rs;
    sfs[tid] = beta[tid] - mu * g * rs;
  }

  // issue B chunks 0,1 then stage X (async, linear dest + inv-swizzled source)
  loadC(bb0, 0);
  if (CH > 1) loadC(bb1, 1);
  asm volatile("" ::: "memory");
  constexpr int ROUNDS = XB / 8192;
#pragma unroll
  for (int r = 0; r < ROUNDS; ++r) {
    int o = r * 8192 + tid * 16;
    int row = o / ROWB;
    int bb = o - row * ROWB;
    int sw = (row & 7) << 4;
    gload_lds16((const char*)X + (size_t)(row0 + row) * ROWB + (bb ^ sw), xs + o);
  }
  __syncthreads();

#pragma unroll
  for (int c = 0; c < CH; ++c) {
    if (c & 1) {
      computeC(bb1, c);
      if (c + 2 < CH) { loadC(bb1, c + 2); asm volatile("" ::: "memory"); }
    } else {
      computeC(bb0, c);
      if (c + 2 < CH) { loadC(bb0, c + 2); asm volatile("" ::: "memory"); }
    }
  }

  // epilogue: store h (bf16) + per-wave logit partials -> LDS -> reduce
  float av = a_s[col0 + m], dv = a_d[col0 + m];
  float sr[4], dr[4];
#pragma unroll
  for (int r = 0; r < 4; ++r) {
    float cc = acc[r];
    hb[(size_t)(row0 + q * 4 + r) * HID + col0 + m] = f2bs(cc);
    sr[r] = cc * av;
    dr[r] = cc * dv;
  }
#pragma unroll
  for (int r = 0; r < 4; ++r) {
#pragma unroll
    for (int off = 1; off < 16; off <<= 1) {
      sr[r] += __shfl_xor(sr[r], off);
      dr[r] += __shfl_xor(dr[r], off);
    }
  }
  if (m == 0) {
#pragma unroll
    for (int r = 0; r < 4; ++r) {
      psA[wid][q * 4 + r] = sr[r];
      psD[wid][q * 4 + r] = dr[r];
    }
  }
  __syncthreads();
  if (tid < 16) {
    float s = 0.f, d = 0.f;
#pragma unroll
    for (int w2 = 0; w2 < 8; ++w2) { s += psA[w2][tid]; d += psD[w2][tid]; }
    asrc[row0 + tid] = s;
    adst[row0 + tid] = d;
  }
}

// ---------------- GAT aggregation (H=128): one wave per node ----------------
// Fast path (deg<=64, ~always for Poisson(17)): SINGLE pass -- one csr read,
// one asrc gather, logits kept in regs, z folded into the gather loop.
// Gather: 4 edges in parallel (16 lanes x 16B row each), 2 in flight.
// Also zeroes the next layer's stats ping-pong buffer (k_zero fused) and
// computes the residual BN scale/shift inline from sums (k_bn_final fused).
__device__ __forceinline__ void acc8(float* a, float e, uint4 v) {
  a[0] += e * bs2f((unsigned short)(v.x & 0xffffu));
  a[1] += e * bs2f((unsigned short)(v.x >> 16));
  a[2] += e * bs2f((unsigned short)(v.y & 0xffffu));
  a[3] += e * bs2f((unsigned short)(v.y >> 16));
  a[4] += e * bs2f((unsigned short)(v.z & 0xffffu));
  a[5] += e * bs2f((unsigned short)(v.z >> 16));
  a[6] += e * bs2f((unsigned short)(v.w & 0xffffu));
  a[7] += e * bs2f((unsigned short)(v.w >> 16));
}

__global__ void k_agg128(const unsigned short* __restrict__ h, const float* __restrict__ asrc,
                         const float* __restrict__ adst, const int* __restrict__ row_ptr,
                         const int* __restrict__ csr_src, const float* __restrict__ bias,
                         const float* __restrict__ hres, const float* __restrict__ stats,
                         const float* __restrict__ gamma, const float* __restrict__ beta,
                         float* __restrict__ out, float* __restrict__ zeroP) {
  __shared__ int   lds_ss[4][64];
  __shared__ float lds_ex[4][64];
  if (zeroP && blockIdx.x == 0 && threadIdx.x < 256) zeroP[threadIdx.x] = 0.0f;
  int wid = (blockIdx.x * blockDim.x + threadIdx.x) >> 6;
  int lane = threadIdx.x & 63;
  int w = (threadIdx.x >> 6) & 3;
  if (wid >= N_NODES) return;
  int beg = row_ptr[wid], end = row_ptr[wid + 1];
  int cnt0 = end - beg;
  float adsti = adst[wid];
  int g = lane & 15, es = lane >> 4;
  float z = 0.f;
  float a[8];
#pragma unroll
  for (int k = 0; k < 8; ++k) a[k] = 0.f;

  if (cnt0 <= 64) {
    int sl = 0;
    float v = -1e30f;
    if (lane < cnt0) {
      sl = clampn(csr_src[beg + lane]);
      v = leaky(asrc[sl] + adsti, 0.2f);
    }
    float mx = v;
#pragma unroll
    for (int off = 1; off < 64; off <<= 1) mx = fmaxf(mx, __shfl_xor(mx, off));
    float ex = (lane < cnt0) ? __expf(v - mx) : 0.f;
    lds_ss[w][lane] = sl;
    lds_ex[w][lane] = ex;
    __builtin_amdgcn_wave_barrier();
    float zs = 0.f;
    for (int jb = 0; jb < cnt0; jb += 8) {
      int j0 = jb + es, j1 = jb + 4 + es;
      int s0 = lds_ss[w][j0]; float e0 = lds_ex[w][j0];
      int s1 = lds_ss[w][j1]; float e1 = lds_ex[w][j1];
      uint4 v0 = *(const uint4*)(h + (size_t)s0 * HID + g * 8);
      uint4 v1 = *(const uint4*)(h + (size_t)s1 * HID + g * 8);
      zs += e0 + e1;
      acc8(a, e0, v0);
      acc8(a, e1, v1);
    }
    z = zs;
  } else {
    float mx = -1e30f;
    for (int cb = beg; cb < end; cb += 64) {
      int e = cb + lane;
      if (e < end) {
        int s = clampn(csr_src[e]);
        mx = fmaxf(mx, leaky(asrc[s] + adsti, 0.2f));
      }
    }
#pragma unroll
    for (int off = 1; off < 64; off <<= 1) mx = fmaxf(mx, __shfl_xor(mx, off));
    float zs = 0.f;
    for (int cb = beg; cb < end; cb += 64) {
      int cnt = min(64, end - cb);
      int sl = 0;
      float ex = 0.f;
      if (lane < cnt) {
        sl = clampn(csr_src[cb + lane]);
        ex = __expf(leaky(asrc[sl] + adsti, 0.2f) - mx);
      }
      lds_ss[w][lane] = sl;
      lds_ex[w][lane] = ex;
      __builtin_amdgcn_wave_barrier();
      for (int jb = 0; jb < cnt; jb += 8) {
        int j0 = jb + es, j1 = jb + 4 + es;
        int s0 = lds_ss[w][j0]; float e0 = lds_ex[w][j0];
        int s1 = lds_ss[w][j1]; float e1 = lds_ex[w][j1];
        uint4 v0 = *(const uint4*)(h + (size_t)s0 * HID + g * 8);
        uint4 v1 = *(const uint4*)(h + (size_t)s1 * HID + g * 8);
        zs += e0 + e1;
        acc8(a, e0, v0);
        acc8(a, e1, v1);
      }
      __builtin_amdgcn_wave_barrier();
    }
    z = zs;
  }
  // combine the 4 edge-slot groups (each holds full 128-col partials)
#pragma unroll
  for (int k = 0; k < 8; ++k) {
    a[k] += __shfl_xor(a[k], 16);
    a[k] += __shfl_xor(a[k], 32);
  }
  z += __shfl_xor(z, 16);
  z += __shfl_xor(z, 32);
  float inv = (z > 0.0f) ? 1.0f / z : 0.0f;
  if (lane < 16) {
    int c0 = g * 8;
    float o[8];
#pragma unroll
    for (int k = 0; k < 8; ++k) o[k] = a[k] * inv + bias[c0 + k];
    if (hres) {
      float hr[8];
      *(float4*)(hr)     = *(const float4*)(hres + (size_t)wid * HID + c0);
      *(float4*)(hr + 4) = *(const float4*)(hres + (size_t)wid * HID + c0 + 4);
#pragma unroll
      for (int k = 0; k < 8; ++k) {
        int c = c0 + k;
        float mu = stats[c] * INV_N;
        float var = fmaxf(stats[HID + c] * INV_N - mu * mu, 0.0f);
        float rs = rsqrtf(var + BN_EPS);
        float sc = gamma[c] * rs;
        float sf = beta[c] - mu * sc;
        o[k] += leaky(hr[k] * sc + sf, 0.1f);
      }
    }
    *(float4*)(out + (size_t)wid * HID + c0)     = *(float4*)(o);
    *(float4*)(out + (size_t)wid * HID + c0 + 4) = *(float4*)(o + 4);
  }
}

// ---------------- BatchNorm stats (into ping-pong stats buffer) ----------------
__global__ void k_bn_stats(const float* __restrict__ h, float* stats) {
  int f = threadIdx.x;  // 128
  int r0 = blockIdx.x * 128;
  int r1 = min(r0 + 128, N_NODES);
  float s = 0.0f, s2 = 0.0f;
#pragma unroll 8
  for (int r = r0; r < r1; ++r) {
    float v = h[(size_t)r * HID + f];
    s += v;
    s2 += v * v;
  }
  atomicAdd(&stats[f], s);
  atomicAdd(&stats[HID + f], s2);
}

// ---------------- final layer GEMM (BN from sums, fused) + alpha logits ----------------
__global__ void k_final_gemm(const float* __restrict__ h, const float* __restrict__ stats,
                             const float* __restrict__ gamma, const float* __restrict__ beta,
                             const float* __restrict__ W4,
                             const float* __restrict__ a4s, const float* __restrict__ a4d,
                             float* __restrict__ h4, float* __restrict__ asrc,
                             float* __restrict__ adst) {
  int row = (blockIdx.x * blockDim.x + threadIdx.x) >> 6;
  int lane = threadIdx.x & 63;
  if (row >= N_NODES) return;
  int c1 = lane + 64;
  float mu0 = stats[lane] * INV_N;
  float va0 = fmaxf(stats[HID + lane] * INV_N - mu0 * mu0, 0.0f);
  float rs0 = rsqrtf(va0 + BN_EPS);
  float sc0 = gamma[lane] * rs0, sf0 = beta[lane] - mu0 * sc0;
  float mu1 = stats[c1] * INV_N;
  float va1 = fmaxf(stats[HID + c1] * INV_N - mu1 * mu1, 0.0f);
  float rs1 = rsqrtf(va1 + BN_EPS);
  float sc1 = gamma[c1] * rs1, sf1 = beta[c1] - mu1 * sc1;
  float t0 = leaky(h[(size_t)row * HID + lane] * sc0 + sf0, 0.1f);
  float t1 = leaky(h[(size_t)row * HID + c1] * sc1 + sf1, 0.1f);
  float myv = 0.0f, s = 0.0f, d = 0.0f;
#pragma unroll
  for (int c = 0; c < N_CLS; ++c) {
    float p = t0 * W4[lane * N_CLS + c] + t1 * W4[(lane + 64) * N_CLS + c];
#pragma unroll
    for (int m = 32; m; m >>= 1) p += __shfl_xor(p, m);
    s += p * a4s[c];
    d += p * a4d[c];
    if (lane == c) myv = p;
  }
  if (lane < N_CLS) h4[(size_t)row * N_CLS + lane] = myv;
  if (lane == 0) { asrc[row] = s; adst[row] = d; }
}

// ---------------- final aggregation (C=9) -> fp32 output ----------------
// Same single-pass fast path; gather 4 edges in parallel (lanes 0-8 of each
// 16-lane group read the 9-col h4 row); z folded into the gather.
__global__ void k_final_agg(const float* __restrict__ h4, const float* __restrict__ asrc,
                            const float* __restrict__ adst, const int* __restrict__ row_ptr,
                            const int* __restrict__ csr_src, const float* __restrict__ b4,
                            float* __restrict__ out) {
  __shared__ int   lds_ss[4][64];
  __shared__ float lds_ex[4][64];
  int wid = (blockIdx.x * blockDim.x + threadIdx.x) >> 6;
  int lane = threadIdx.x & 63;
  int w = (threadIdx.x >> 6) & 3;
  if (wid >= N_NODES) return;
  int beg = row_ptr[wid], end = row_ptr[wid + 1];
  int cnt0 = end - beg;
  float adsti = adst[wid];
  int g = lane & 15, es = lane >> 4;
  float zs = 0.f, av = 0.f;
  if (cnt0 <= 64) {
    int sl = 0;
    float v = -1e30f;
    if (lane < cnt0) {
      sl = clampn(csr_src[beg + lane]);
      v = leaky(asrc[sl] + adsti, 0.2f);
    }
    float mx = v;
#pragma unroll
    for (int off = 1; off < 64; off <<= 1) mx = fmaxf(mx, __shfl_xor(mx, off));
    float ex = (lane < cnt0) ? __expf(v - mx) : 0.f;
    lds_ss[w][lane] = sl;
    lds_ex[w][lane] = ex;
    __builtin_amdgcn_wave_barrier();
    for (int jb = 0; jb < cnt0; jb += 4) {
      int j = jb + es;
      int s = lds_ss[w][j];
      float e = lds_ex[w][j];
      zs += e;
      if (g < N_CLS) av += e * h4[(size_t)s * N_CLS + g];
    }
  } else {
    float mx = -1e30f;
    for (int cb = beg; cb < end; cb += 64) {
      int e = cb + lane;
      if (e < end) {
        int s = clampn(csr_src[e]);
        mx = fmaxf(mx, leaky(asrc[s] + adsti, 0.2f));
      }
    }
#pragma unroll
    for (int off = 1; off < 64; off <<= 1) mx = fmaxf(mx, __shfl_xor(mx, off));
    for (int cb = beg; cb < end; cb += 64) {
      int cnt = min(64, end - cb);
      int sl = 0;
      float ex = 0.f;
      if (lane < cnt) {
        sl = clampn(csr_src[cb + lane]);
        ex = __expf(leaky(asrc[sl] + adsti, 0.2f) - mx);
      }
      lds_ss[w][lane] = sl;
      lds_ex[w][lane] = ex;
      __builtin_amdgcn_wave_barrier();
      for (int jb = 0; jb < cnt; jb += 4) {
        int j = jb + es;
        int s = lds_ss[w][j];
        float e = lds_ex[w][j];
        zs += e;
        if (g < N_CLS) av += e * h4[(size_t)s * N_CLS + g];
      }
      __builtin_amdgcn_wave_barrier();
    }
  }
  float z = zs;
  z += __shfl_xor(z, 16); z += __shfl_xor(z, 32);
  av += __shfl_xor(av, 16); av += __shfl_xor(av, 32);
  if (lane < N_CLS) {
    float o = (z > 0.0f) ? av / z : 0.0f;
    o = leaky(o + b4[lane], 0.1f);
    out[(size_t)wid * N_CLS + lane] = o;
  }
}

extern "C" void kernel_launch(void* const* d_in, const int* in_sizes, int n_in,
                              void* d_out, int out_size, void* d_ws, size_t ws_size,
                              hipStream_t stream) {
  const float* x   = (const float*)d_in[0];
  const int*   ei  = (const int*)d_in[1];
  const int*   src = ei;
  const int*   dst = ei + N_EDGES;
  const float* W0  = (const float*)d_in[4];
  const float* a0s = (const float*)d_in[5];
  const float* a0d = (const float*)d_in[6];
  const float* b0  = (const float*)d_in[7];
  const float* Wm  = (const float*)d_in[8];
  const float* ams = (const float*)d_in[9];
  const float* amd = (const float*)d_in[10];
  const float* bm  = (const float*)d_in[11];
  const float* W4  = (const float*)d_in[12];
  const float* a4s = (const float*)d_in[13];
  const float* a4d = (const float*)d_in[14];
  const float* b4  = (const float*)d_in[15];
  const float* gam = (const float*)d_in[16];
  const float* bet = (const float*)d_in[17];
  float* out = (float*)d_out;

  // ---- workspace layout (~45 MB) ----
  int* row_ptr   = (int*)d_ws;                    // 50001 (pad 50004)
  int* fill      = row_ptr + 50004;               // N
  int* csr_src   = fill + N_NODES;                // ETOT
  short* W0T     = (short*)(csr_src + ETOT);      // 98304
  short* WmT     = W0T + F_INN * HID;             // 49152
  short* bufA    = WmT + 3 * HID * HID;           // N*128 bf16 (pre-agg h)
  float* asrc    = (float*)(bufA + (size_t)N_NODES * HID);  // N
  float* adst    = asrc + N_NODES;                // N
  float* pstat   = adst + N_NODES;                // 512 (2x ping-pong sum[128]+sumsq[128])
  float* h4      = pstat + 512;                   // N*9
  float* bufB    = h4 + (size_t)N_NODES * N_CLS;  // N*128 fp32 (running h)
  float* PST[2]  = {pstat, pstat + 256};

  const int B256 = 256;
  int gN    = (N_NODES + B256 - 1) / B256;
  int gE    = (N_EDGES + B256 - 1) / B256;
  int gET   = (ETOT + B256 - 1) / B256;
  int gWav  = (N_NODES + 3) / 4;
  int gMfma = N_NODES / 16;   // 3125 blocks x 512 threads (exact)
  int gBN   = (N_NODES + 127) / 128;
  int gPack = (F_INN * HID + 3 * HID * HID + B256 - 1) / B256;

  // ---- pack weights + CSR ----
  k_pack<<<gPack, B256, 0, stream>>>(W0, Wm, W0T, WmT);
  k_init_deg<<<gN, B256, 0, stream>>>(fill);
  k_count<<<gE, B256, 0, stream>>>(dst, fill);
  k_scan<<<1, 1024, 0, stream>>>(fill, row_ptr);
  k_place<<<gET, B256, 0, stream>>>(src, dst, row_ptr, fill, csr_src);

  // ---- layer 0: h = GAT(x, W0, a0) + b0 -> bufB; agg zeroes PST[0] ----
  k_gemm_mfma<F_INN, false><<<gMfma, 512, 0, stream>>>(x, W0T, nullptr, nullptr, nullptr,
                                                       a0s, a0d, bufA, asrc, adst);
  k_agg128<<<gWav, B256, 0, stream>>>((const unsigned short*)bufA, asrc, adst, row_ptr,
                                      csr_src, b0, nullptr, nullptr, nullptr, nullptr,
                                      bufB, PST[0]);

  // ---- mid layers: t = leaky(bn(h),0.1) fused into GEMM; h = GAT(t) + t ----
  for (int i = 0; i < 3; ++i) {
    k_bn_stats<<<gBN, HID, 0, stream>>>(bufB, PST[i & 1]);
    k_gemm_mfma<HID, true><<<gMfma, 512, 0, stream>>>(bufB, WmT + i * HID * HID,
                                                      PST[i & 1], gam + i * HID, bet + i * HID,
                                                      ams + i * HID, amd + i * HID,
                                                      bufA, asrc, adst);
    k_agg128<<<gWav, B256, 0, stream>>>((const unsigned short*)bufA, asrc, adst, row_ptr,
                                        csr_src, bm + i * HID, bufB, PST[i & 1],
                                        gam + i * HID, bet + i * HID, bufB, PST[(i + 1) & 1]);
  }

  // ---- final: t = leaky(bn(h),0.1); out = leaky(GAT(t, W4), 0.1) ----
  k_bn_stats<<<gBN, HID, 0, stream>>>(bufB, PST[1]);
  k_final_gemm<<<gWav, B256, 0, stream>>>(bufB, PST[1], gam + 3 * HID, bet + 3 * HID,
                                          W4, a4s, a4d, h4, asrc, adst);
  k_final_agg<<<gWav, B256, 0, stream>>>(h4, asrc, adst, row_ptr, csr_src, b4, out);
}

// Round 6
// 775.365 us; speedup vs baseline: 1.3931x; 1.0421x over previous
//
#include <hip/hip_runtime.h>
#include <hip/hip_bf16.h>

#define N_NODES 50000
#define N_EDGES 800000
#define F_INN   768
#define HID     128
#define N_CLS   9
#define ETOT    (N_EDGES + N_NODES)
#define BN_EPS  1e-5f
#define INV_N   (1.0f / (float)N_NODES)
#define NT16    (N_NODES / 16)   // 3125 row-tiles, exact

typedef __hip_bfloat16 bf16;
typedef __attribute__((ext_vector_type(8))) short bf16x8;
typedef __attribute__((ext_vector_type(4))) float f32x4;

__device__ __forceinline__ float leaky(float v, float s) { return v >= 0.0f ? v : s * v; }
__device__ __forceinline__ int clampn(int s) {
  return ((unsigned)s < (unsigned)N_NODES) ? s : 0;
}
__device__ __forceinline__ short f2bs(float f) {
  bf16 h = __float2bfloat16(f);
  return __builtin_bit_cast(short, h);
}
__device__ __forceinline__ float bs2f(unsigned short u) {
  unsigned v = ((unsigned)u) << 16;
  return __builtin_bit_cast(float, v);
}
__device__ __forceinline__ void gload_lds16(const void* g, void* l) {
  __builtin_amdgcn_global_load_lds((const __attribute__((address_space(1))) void*)g,
                                   (__attribute__((address_space(3))) void*)l, 16, 0, 0);
}
__device__ __forceinline__ void blk_barrier() {
  asm volatile("" ::: "memory");
  __builtin_amdgcn_s_barrier();
  __builtin_amdgcn_sched_barrier(0);
}
__device__ __forceinline__ void lgkm0() {
  asm volatile("s_waitcnt lgkmcnt(0)" ::: "memory");
}

// ---------------- pack W0^T, Wm^T to bf16 [n][k] ----------------
__global__ void k_pack(const float* __restrict__ W0, const float* __restrict__ Wm,
                       short* __restrict__ W0T, short* __restrict__ WmT) {
  int i = blockIdx.x * blockDim.x + threadIdx.x;
  if (i < F_INN * HID) {
    int n = i / F_INN, k = i % F_INN;
    W0T[i] = f2bs(W0[k * HID + n]);
  } else if (i < F_INN * HID + 3 * HID * HID) {
    int j = i - F_INN * HID;
    int l = j / (HID * HID), rem = j % (HID * HID);
    int n = rem / HID, k = rem % HID;
    WmT[j] = f2bs(Wm[(l * HID + k) * HID + n]);
  }
}

// ---------------- CSR build ----------------
__global__ void k_init_deg(int* fill) {
  int i = blockIdx.x * blockDim.x + threadIdx.x;
  if (i < N_NODES) fill[i] = 1;  // self-loop
}

__global__ void k_count(const int* __restrict__ dst, int* fill) {
  int e = blockIdx.x * blockDim.x + threadIdx.x;
  if (e < N_EDGES) atomicAdd(&fill[clampn(dst[e])], 1);
}

// shuffle-based scan: 3 barriers per 1024-chunk
__global__ void k_scan(int* fill, int* row_ptr) {
  __shared__ int wsum[16], wpre[16];
  int tid = threadIdx.x, lane = tid & 63, wv = tid >> 6;
  int carry = 0;
  for (int base = 0; base < N_NODES; base += 1024) {
    int i = base + tid;
    int v = (i < N_NODES) ? fill[i] : 0;
    if (i < N_NODES) fill[i] = 0;
    int sc = v;
#pragma unroll
    for (int off = 1; off < 64; off <<= 1) {
      int t = __shfl_up(sc, off);
      if (lane >= off) sc += t;
    }
    if (lane == 63) wsum[wv] = sc;
    __syncthreads();
    if (tid < 16) {
      int s = wsum[tid];
#pragma unroll
      for (int off = 1; off < 16; off <<= 1) {
        int t = __shfl_up(s, off);
        if (tid >= off) s += t;
      }
      wpre[tid] = s;
    }
    __syncthreads();
    int woff = wv ? wpre[wv - 1] : 0;
    if (i < N_NODES) row_ptr[i] = carry + woff + sc - v;
    carry += wpre[15];
    __syncthreads();
  }
  if (tid == 0) row_ptr[N_NODES] = carry;
}

__global__ void k_place(const int* __restrict__ src, const int* __restrict__ dst,
                        const int* __restrict__ row_ptr, int* fill, int* csr_src) {
  int id = blockIdx.x * blockDim.x + threadIdx.x;
  if (id >= ETOT) return;
  int s, d;
  if (id < N_EDGES) { s = clampn(src[id]); d = clampn(dst[id]); }
  else { s = id - N_EDGES; d = s; }
  int p = atomicAdd(&fill[d], 1);
  csr_src[row_ptr[d] + p] = s;
}

// ---------------- MFMA GEMM: persistent blocks, B-in-regs, staged-convert ----------------
// 256 blocks (1/CU) x 512 thr; block grid-strides over ~12 row-tiles of 16 rows.
// B loaded ONCE per block into regs (wave w owns cols w*16..+15; 24 bf16x8 = 96 VGPR
// at K=768). Per tile (K split into KSUB=384 halves to fit LDS):
//   vmcnt(LPT) [stage(t) landed; stage(t+2)'s LPT may fly] -> barrier
//   convert bufF[t&1] -> bufH once, cooperatively (kills 8x duplicated cvt VALU)
//   lgkmcnt(0) -> barrier -> issue STAGE(t+2) into bufF[t&1] (now free) -> MFMA
// All LDS layouts are lane-linear 16B slots (measured-zero-conflict pattern).
// vmcnt counting is robust: younger stray ops only make the wait stricter.
template <int K, bool BN>
__global__ __launch_bounds__(512, 2)
void k_gemm_mfma(const float* __restrict__ X, const short* __restrict__ BT,
                 const float* __restrict__ stats, const float* __restrict__ gamma,
                 const float* __restrict__ beta,
                 const float* __restrict__ a_s, const float* __restrict__ a_d,
                 short* __restrict__ hb, float* __restrict__ asrc,
                 float* __restrict__ adst) {
  constexpr int KSUB  = (K > 384) ? 384 : K;  // staged K-chunk
  constexpr int NSUB  = K / KSUB;             // 2 (K=768) or 1 (K=128)
  constexpr int NS    = KSUB / 32;            // MFMA steps per subtile
  constexpr int LPT   = KSUB / 128;           // gload_lds per thread per stage
  constexpr int NSLOT = KSUB * 2;             // bufH 16B slots
  __shared__ float4 bufF[2][KSUB * 4];        // fp32 X subtile, double-buffered
  __shared__ bf16x8 bufH[NSLOT];              // converted A-fragments, lane-linear
  __shared__ float scs[HID], sfs[HID];
  __shared__ float psA[8][16], psD[8][16];

  const int tid = threadIdx.x;
  const int wv = tid >> 6, lane = tid & 63;
  const int m = lane & 15, q = lane >> 4;
  const int col = wv * 16 + m;
  const int bid = blockIdx.x;
  const int nrt = (NT16 - bid + 255) >> 8;    // row-tiles for this block
  const int T = nrt * NSUB;

  // ---- B into registers: 16 cols per wave, full K, loaded once ----
  bf16x8 breg[K / 32];
  {
    const short* bb = BT + (size_t)col * K + q * 8;
#pragma unroll
    for (int c = 0; c < K / 32; ++c) breg[c] = *(const bf16x8*)(bb + c * 32);
  }
  const float av = a_s[col], dv = a_d[col];

  if (BN && tid < HID) {
    float mu = stats[tid] * INV_N;
    float var = fmaxf(stats[HID + tid] * INV_N - mu * mu, 0.0f);
    float rs = rsqrtf(var + BN_EPS);
    float g2 = gamma[tid];
    scs[tid] = g2 * rs;
    sfs[tid] = beta[tid] - mu * g2 * rs;
  }

  auto STAGE = [&](int t) {
    int r0 = (bid + (t / NSUB) * 256) * 16;
    int kb = (NSUB == 2) ? (t & 1) * KSUB : 0;
    int buf = t & 1;
#pragma unroll
    for (int r = 0; r < LPT; ++r) {
      int d = r * 512 + tid;
      int row = d & 15, c = d >> 4;       // bufF[d] = X[r0+row][kb + c*4 .. +3]
      gload_lds16(X + (size_t)(r0 + row) * K + kb + c * 4, &bufF[buf][d]);
    }
  };

  STAGE(0);
  if (T > 1) STAGE(1);
  lgkm0();          // scs/sfs writes drained
  blk_barrier();

  f32x4 acc = (f32x4){0.f, 0.f, 0.f, 0.f};
  for (int t = 0; t < T; ++t) {
    const int ks = (NSUB == 2) ? (t & 1) : 0;
    const int buf = t & 1;
    // wait: stage(t) landed (stage(t+1)/(t+2) may remain in flight)
    if (t + 1 < T) {
      if constexpr (LPT == 3) asm volatile("s_waitcnt vmcnt(3)" ::: "memory");
      else                    asm volatile("s_waitcnt vmcnt(1)" ::: "memory");
    } else {
      asm volatile("s_waitcnt vmcnt(0)" ::: "memory");
    }
    blk_barrier();
    // ---- convert (once, cooperatively): bufF[buf] -> bufH ----
#pragma unroll
    for (int j = 0; j < (NSLOT + 511) / 512; ++j) {
      int sl = j * 512 + tid;
      if (sl < NSLOT) {
        int s = sl >> 6, lp = sl & 63;
        int mp = lp & 15, qp = lp >> 4;
        int k0 = s * 32 + qp * 8;
        int d = (k0 >> 2) * 16 + mp;
        float4 x0 = bufF[buf][d];
        float4 x1 = bufF[buf][d + 16];
        float xv[8] = {x0.x, x0.y, x0.z, x0.w, x1.x, x1.y, x1.z, x1.w};
        if (BN) {
#pragma unroll
          for (int jj = 0; jj < 8; ++jj)
            xv[jj] = leaky(xv[jj] * scs[k0 + jj] + sfs[k0 + jj], 0.1f);
        }
        bf16x8 hv;
#pragma unroll
        for (int jj = 0; jj < 8; ++jj) hv[jj] = f2bs(xv[jj]);
        bufH[sl] = hv;
      }
    }
    lgkm0();
    blk_barrier();
    // bufF[buf] free now: prefetch 2 tiles ahead (overlaps MFMA below)
    if (t + 2 < T) STAGE(t + 2);
    // ---- compute: NS MFMA per wave, A from lane-linear bufH ----
    if (NSUB == 2 && ks == 1) {
#pragma unroll
      for (int s = 0; s < NS; ++s)
        acc = __builtin_amdgcn_mfma_f32_16x16x32_bf16(bufH[s * 64 + lane],
                                                      breg[NS + s], acc, 0, 0, 0);
    } else {
#pragma unroll
      for (int s = 0; s < NS; ++s)
        acc = __builtin_amdgcn_mfma_f32_16x16x32_bf16(bufH[s * 64 + lane],
                                                      breg[s], acc, 0, 0, 0);
    }
    // ---- epilogue on last K-half: h store + attention logits ----
    if (ks == NSUB - 1) {
      int r0 = (bid + (t / NSUB) * 256) * 16;
      float sr[4], dr[4];
#pragma unroll
      for (int r = 0; r < 4; ++r) {
        float cc = acc[r];
        hb[(size_t)(r0 + q * 4 + r) * HID + col] = f2bs(cc);
        sr[r] = cc * av;
        dr[r] = cc * dv;
      }
      acc = (f32x4){0.f, 0.f, 0.f, 0.f};
#pragma unroll
      for (int r = 0; r < 4; ++r) {
#pragma unroll
        for (int off = 1; off < 16; off <<= 1) {
          sr[r] += __shfl_xor(sr[r], off);
          dr[r] += __shfl_xor(dr[r], off);
        }
      }
      if (m == 0) {
#pragma unroll
        for (int r = 0; r < 4; ++r) {
          psA[wv][q * 4 + r] = sr[r];
          psD[wv][q * 4 + r] = dr[r];
        }
      }
      lgkm0();
      blk_barrier();
      if (tid < 16) {
        float s2 = 0.f, d2 = 0.f;
#pragma unroll
        for (int w2 = 0; w2 < 8; ++w2) { s2 += psA[w2][tid]; d2 += psD[w2][tid]; }
        asrc[r0 + tid] = s2;
        adst[r0 + tid] = d2;
      }
    }
  }
}

// ---------------- GAT aggregation (H=128): one wave per node ----------------
// Fast path (deg<=64): single pass; gather loop 2-deep pipelined (round
// r+1's two h-rows load while round r's FMAs run). Slots >= cnt carry ex=0.
__device__ __forceinline__ void acc8(float* a, float e, uint4 v) {
  a[0] += e * bs2f((unsigned short)(v.x & 0xffffu));
  a[1] += e * bs2f((unsigned short)(v.x >> 16));
  a[2] += e * bs2f((unsigned short)(v.y & 0xffffu));
  a[3] += e * bs2f((unsigned short)(v.y >> 16));
  a[4] += e * bs2f((unsigned short)(v.z & 0xffffu));
  a[5] += e * bs2f((unsigned short)(v.z >> 16));
  a[6] += e * bs2f((unsigned short)(v.w & 0xffffu));
  a[7] += e * bs2f((unsigned short)(v.w >> 16));
}

__global__ void k_agg128(const unsigned short* __restrict__ h, const float* __restrict__ asrc,
                         const float* __restrict__ adst, const int* __restrict__ row_ptr,
                         const int* __restrict__ csr_src, const float* __restrict__ bias,
                         const float* __restrict__ hres, const float* __restrict__ stats,
                         const float* __restrict__ gamma, const float* __restrict__ beta,
                         float* __restrict__ out, float* __restrict__ zeroP) {
  __shared__ int   lds_ss[4][64];
  __shared__ float lds_ex[4][64];
  if (zeroP && blockIdx.x == 0 && threadIdx.x < 256) zeroP[threadIdx.x] = 0.0f;
  int wid = (blockIdx.x * blockDim.x + threadIdx.x) >> 6;
  int lane = threadIdx.x & 63;
  int w = (threadIdx.x >> 6) & 3;
  if (wid >= N_NODES) return;
  int beg = row_ptr[wid], end = row_ptr[wid + 1];
  int cnt0 = end - beg;
  float adsti = adst[wid];
  int g = lane & 15, es = lane >> 4;
  float z = 0.f;
  float a[8];
#pragma unroll
  for (int k = 0; k < 8; ++k) a[k] = 0.f;

  if (cnt0 <= 64) {
    int sl = 0;
    float v = -1e30f;
    if (lane < cnt0) {
      sl = clampn(csr_src[beg + lane]);
      v = leaky(asrc[sl] + adsti, 0.2f);
    }
    float mx = v;
#pragma unroll
    for (int off = 1; off < 64; off <<= 1) mx = fmaxf(mx, __shfl_xor(mx, off));
    float ex = (lane < cnt0) ? __expf(v - mx) : 0.f;
    lds_ss[w][lane] = sl;
    lds_ex[w][lane] = ex;
    __builtin_amdgcn_wave_barrier();
    int nr = (cnt0 + 7) >> 3;
    int s0 = lds_ss[w][es],     s1 = lds_ss[w][es + 4];
    float e0 = lds_ex[w][es],   e1 = lds_ex[w][es + 4];
    uint4 v0 = *(const uint4*)(h + (size_t)s0 * HID + g * 8);
    uint4 v1 = *(const uint4*)(h + (size_t)s1 * HID + g * 8);
    float zs = 0.f;
    for (int r = 1; r < nr; ++r) {
      int j0 = r * 8 + es, j1 = r * 8 + 4 + es;
      int t0 = lds_ss[w][j0];   float f0 = lds_ex[w][j0];
      int t1 = lds_ss[w][j1];   float f1 = lds_ex[w][j1];
      uint4 n0 = *(const uint4*)(h + (size_t)t0 * HID + g * 8);
      uint4 n1 = *(const uint4*)(h + (size_t)t1 * HID + g * 8);
      zs += e0 + e1;
      acc8(a, e0, v0);
      acc8(a, e1, v1);
      v0 = n0; v1 = n1; e0 = f0; e1 = f1;
    }
    zs += e0 + e1;
    acc8(a, e0, v0);
    acc8(a, e1, v1);
    z = zs;
  } else {
    float mx = -1e30f;
    for (int cb = beg; cb < end; cb += 64) {
      int e = cb + lane;
      if (e < end) {
        int s = clampn(csr_src[e]);
        mx = fmaxf(mx, leaky(asrc[s] + adsti, 0.2f));
      }
    }
#pragma unroll
    for (int off = 1; off < 64; off <<= 1) mx = fmaxf(mx, __shfl_xor(mx, off));
    float zs = 0.f;
    for (int cb = beg; cb < end; cb += 64) {
      int cnt = min(64, end - cb);
      int sl = 0;
      float ex = 0.f;
      if (lane < cnt) {
        sl = clampn(csr_src[cb + lane]);
        ex = __expf(leaky(asrc[sl] + adsti, 0.2f) - mx);
      }
      lds_ss[w][lane] = sl;
      lds_ex[w][lane] = ex;
      __builtin_amdgcn_wave_barrier();
      for (int jb = 0; jb < cnt; jb += 8) {
        int j0 = jb + es, j1 = jb + 4 + es;
        int s0 = lds_ss[w][j0]; float e0 = lds_ex[w][j0];
        int s1 = lds_ss[w][j1]; float e1 = lds_ex[w][j1];
        uint4 v0 = *(const uint4*)(h + (size_t)s0 * HID + g * 8);
        uint4 v1 = *(const uint4*)(h + (size_t)s1 * HID + g * 8);
        zs += e0 + e1;
        acc8(a, e0, v0);
        acc8(a, e1, v1);
      }
      __builtin_amdgcn_wave_barrier();
    }
    z = zs;
  }
#pragma unroll
  for (int k = 0; k < 8; ++k) {
    a[k] += __shfl_xor(a[k], 16);
    a[k] += __shfl_xor(a[k], 32);
  }
  z += __shfl_xor(z, 16);
  z += __shfl_xor(z, 32);
  float inv = (z > 0.0f) ? 1.0f / z : 0.0f;
  if (lane < 16) {
    int c0 = g * 8;
    float o[8];
#pragma unroll
    for (int k = 0; k < 8; ++k) o[k] = a[k] * inv + bias[c0 + k];
    if (hres) {
      float hr[8];
      *(float4*)(hr)     = *(const float4*)(hres + (size_t)wid * HID + c0);
      *(float4*)(hr + 4) = *(const float4*)(hres + (size_t)wid * HID + c0 + 4);
#pragma unroll
      for (int k = 0; k < 8; ++k) {
        int c = c0 + k;
        float mu = stats[c] * INV_N;
        float var = fmaxf(stats[HID + c] * INV_N - mu * mu, 0.0f);
        float rs = rsqrtf(var + BN_EPS);
        float sc = gamma[c] * rs;
        float sf = beta[c] - mu * sc;
        o[k] += leaky(hr[k] * sc + sf, 0.1f);
      }
    }
    *(float4*)(out + (size_t)wid * HID + c0)     = *(float4*)(o);
    *(float4*)(out + (size_t)wid * HID + c0 + 4) = *(float4*)(o + 4);
  }
}

// ---------------- BatchNorm stats (into ping-pong stats buffer) ----------------
__global__ void k_bn_stats(const float* __restrict__ h, float* stats) {
  int f = threadIdx.x;  // 128
  int r0 = blockIdx.x * 128;
  int r1 = min(r0 + 128, N_NODES);
  float s = 0.0f, s2 = 0.0f;
#pragma unroll 8
  for (int r = r0; r < r1; ++r) {
    float v = h[(size_t)r * HID + f];
    s += v;
    s2 += v * v;
  }
  atomicAdd(&stats[f], s);
  atomicAdd(&stats[HID + f], s2);
}

// ---------------- final layer GEMM (BN from sums, fused) + alpha logits ----------------
__global__ void k_final_gemm(const float* __restrict__ h, const float* __restrict__ stats,
                             const float* __restrict__ gamma, const float* __restrict__ beta,
                             const float* __restrict__ W4,
                             const float* __restrict__ a4s, const float* __restrict__ a4d,
                             float* __restrict__ h4, float* __restrict__ asrc,
                             float* __restrict__ adst) {
  int row = (blockIdx.x * blockDim.x + threadIdx.x) >> 6;
  int lane = threadIdx.x & 63;
  if (row >= N_NODES) return;
  int c1 = lane + 64;
  float mu0 = stats[lane] * INV_N;
  float va0 = fmaxf(stats[HID + lane] * INV_N - mu0 * mu0, 0.0f);
  float rs0 = rsqrtf(va0 + BN_EPS);
  float sc0 = gamma[lane] * rs0, sf0 = beta[lane] - mu0 * sc0;
  float mu1 = stats[c1] * INV_N;
  float va1 = fmaxf(stats[HID + c1] * INV_N - mu1 * mu1, 0.0f);
  float rs1 = rsqrtf(va1 + BN_EPS);
  float sc1 = gamma[c1] * rs1, sf1 = beta[c1] - mu1 * sc1;
  float t0 = leaky(h[(size_t)row * HID + lane] * sc0 + sf0, 0.1f);
  float t1 = leaky(h[(size_t)row * HID + c1] * sc1 + sf1, 0.1f);
  float myv = 0.0f, s = 0.0f, d = 0.0f;
#pragma unroll
  for (int c = 0; c < N_CLS; ++c) {
    float p = t0 * W4[lane * N_CLS + c] + t1 * W4[(lane + 64) * N_CLS + c];
#pragma unroll
    for (int m = 32; m; m >>= 1) p += __shfl_xor(p, m);
    s += p * a4s[c];
    d += p * a4d[c];
    if (lane == c) myv = p;
  }
  if (lane < N_CLS) h4[(size_t)row * N_CLS + lane] = myv;
  if (lane == 0) { asrc[row] = s; adst[row] = d; }
}

// ---------------- final aggregation (C=9) -> fp32 output ----------------
__global__ void k_final_agg(const float* __restrict__ h4, const float* __restrict__ asrc,
                            const float* __restrict__ adst, const int* __restrict__ row_ptr,
                            const int* __restrict__ csr_src, const float* __restrict__ b4,
                            float* __restrict__ out) {
  __shared__ int   lds_ss[4][64];
  __shared__ float lds_ex[4][64];
  int wid = (blockIdx.x * blockDim.x + threadIdx.x) >> 6;
  int lane = threadIdx.x & 63;
  int w = (threadIdx.x >> 6) & 3;
  if (wid >= N_NODES) return;
  int beg = row_ptr[wid], end = row_ptr[wid + 1];
  int cnt0 = end - beg;
  float adsti = adst[wid];
  int g = lane & 15, es = lane >> 4;
  float zs = 0.f, av = 0.f;
  if (cnt0 <= 64) {
    int sl = 0;
    float v = -1e30f;
    if (lane < cnt0) {
      sl = clampn(csr_src[beg + lane]);
      v = leaky(asrc[sl] + adsti, 0.2f);
    }
    float mx = v;
#pragma unroll
    for (int off = 1; off < 64; off <<= 1) mx = fmaxf(mx, __shfl_xor(mx, off));
    float ex = (lane < cnt0) ? __expf(v - mx) : 0.f;
    lds_ss[w][lane] = sl;
    lds_ex[w][lane] = ex;
    __builtin_amdgcn_wave_barrier();
    int nr = (cnt0 + 3) >> 2;
    int s0 = lds_ss[w][es];
    float e0 = lds_ex[w][es];
    float hv0 = (g < N_CLS) ? h4[(size_t)s0 * N_CLS + g] : 0.f;
    for (int r = 1; r < nr; ++r) {
      int j = r * 4 + es;
      int s1 = lds_ss[w][j];
      float e1 = lds_ex[w][j];
      float hv1 = (g < N_CLS) ? h4[(size_t)s1 * N_CLS + g] : 0.f;
      zs += e0;
      av += e0 * hv0;
      s0 = s1; e0 = e1; hv0 = hv1;
    }
    zs += e0;
    av += e0 * hv0;
  } else {
    float mx = -1e30f;
    for (int cb = beg; cb < end; cb += 64) {
      int e = cb + lane;
      if (e < end) {
        int s = clampn(csr_src[e]);
        mx = fmaxf(mx, leaky(asrc[s] + adsti, 0.2f));
      }
    }
#pragma unroll
    for (int off = 1; off < 64; off <<= 1) mx = fmaxf(mx, __shfl_xor(mx, off));
    for (int cb = beg; cb < end; cb += 64) {
      int cnt = min(64, end - cb);
      int sl = 0;
      float ex = 0.f;
      if (lane < cnt) {
        sl = clampn(csr_src[cb + lane]);
        ex = __expf(leaky(asrc[sl] + adsti, 0.2f) - mx);
      }
      lds_ss[w][lane] = sl;
      lds_ex[w][lane] = ex;
      __builtin_amdgcn_wave_barrier();
      for (int jb = 0; jb < cnt; jb += 4) {
        int j = jb + es;
        int s = lds_ss[w][j];
        float e = lds_ex[w][j];
        zs += e;
        if (g < N_CLS) av += e * h4[(size_t)s * N_CLS + g];
      }
      __builtin_amdgcn_wave_barrier();
    }
  }
  float z = zs;
  z += __shfl_xor(z, 16); z += __shfl_xor(z, 32);
  av += __shfl_xor(av, 16); av += __shfl_xor(av, 32);
  if (lane < N_CLS) {
    float o = (z > 0.0f) ? av / z : 0.0f;
    o = leaky(o + b4[lane], 0.1f);
    out[(size_t)wid * N_CLS + lane] = o;
  }
}

extern "C" void kernel_launch(void* const* d_in, const int* in_sizes, int n_in,
                              void* d_out, int out_size, void* d_ws, size_t ws_size,
                              hipStream_t stream) {
  const float* x   = (const float*)d_in[0];
  const int*   ei  = (const int*)d_in[1];
  const int*   src = ei;
  const int*   dst = ei + N_EDGES;
  const float* W0  = (const float*)d_in[4];
  const float* a0s = (const float*)d_in[5];
  const float* a0d = (const float*)d_in[6];
  const float* b0  = (const float*)d_in[7];
  const float* Wm  = (const float*)d_in[8];
  const float* ams = (const float*)d_in[9];
  const float* amd = (const float*)d_in[10];
  const float* bm  = (const float*)d_in[11];
  const float* W4  = (const float*)d_in[12];
  const float* a4s = (const float*)d_in[13];
  const float* a4d = (const float*)d_in[14];
  const float* b4  = (const float*)d_in[15];
  const float* gam = (const float*)d_in[16];
  const float* bet = (const float*)d_in[17];
  float* out = (float*)d_out;

  // ---- workspace layout (~45 MB) ----
  int* row_ptr   = (int*)d_ws;                    // 50001 (pad 50004)
  int* fill      = row_ptr + 50004;               // N
  int* csr_src   = fill + N_NODES;                // ETOT
  short* W0T     = (short*)(csr_src + ETOT);      // 98304
  short* WmT     = W0T + F_INN * HID;             // 49152
  short* bufA    = WmT + 3 * HID * HID;           // N*128 bf16 (pre-agg h)
  float* asrc    = (float*)(bufA + (size_t)N_NODES * HID);  // N
  float* adst    = asrc + N_NODES;                // N
  float* pstat   = adst + N_NODES;                // 512 (2x ping-pong sum+sumsq)
  float* h4      = pstat + 512;                   // N*9
  float* bufB    = h4 + (size_t)N_NODES * N_CLS;  // N*128 fp32 (running h)
  float* PST[2]  = {pstat, pstat + 256};

  const int B256 = 256;
  int gN    = (N_NODES + B256 - 1) / B256;
  int gE    = (N_EDGES + B256 - 1) / B256;
  int gET   = (ETOT + B256 - 1) / B256;
  int gWav  = (N_NODES + 3) / 4;
  int gBN   = (N_NODES + 127) / 128;
  int gPack = (F_INN * HID + 3 * HID * HID + B256 - 1) / B256;

  // ---- pack weights + CSR ----
  k_pack<<<gPack, B256, 0, stream>>>(W0, Wm, W0T, WmT);
  k_init_deg<<<gN, B256, 0, stream>>>(fill);
  k_count<<<gE, B256, 0, stream>>>(dst, fill);
  k_scan<<<1, 1024, 0, stream>>>(fill, row_ptr);
  k_place<<<gET, B256, 0, stream>>>(src, dst, row_ptr, fill, csr_src);

  // ---- layer 0: h = GAT(x, W0, a0) + b0 -> bufB; agg zeroes PST[0] ----
  k_gemm_mfma<F_INN, false><<<256, 512, 0, stream>>>(x, W0T, nullptr, nullptr, nullptr,
                                                     a0s, a0d, bufA, asrc, adst);
  k_agg128<<<gWav, B256, 0, stream>>>((const unsigned short*)bufA, asrc, adst, row_ptr,
                                      csr_src, b0, nullptr, nullptr, nullptr, nullptr,
                                      bufB, PST[0]);

  // ---- mid layers: t = leaky(bn(h),0.1) fused into GEMM; h = GAT(t) + t ----
  for (int i = 0; i < 3; ++i) {
    k_bn_stats<<<gBN, HID, 0, stream>>>(bufB, PST[i & 1]);
    k_gemm_mfma<HID, true><<<256, 512, 0, stream>>>(bufB, WmT + i * HID * HID,
                                                    PST[i & 1], gam + i * HID, bet + i * HID,
                                                    ams + i * HID, amd + i * HID,
                                                    bufA, asrc, adst);
    k_agg128<<<gWav, B256, 0, stream>>>((const unsigned short*)bufA, asrc, adst, row_ptr,
                                        csr_src, bm + i * HID, bufB, PST[i & 1],
                                        gam + i * HID, bet + i * HID, bufB, PST[(i + 1) & 1]);
  }

  // ---- final: t = leaky(bn(h),0.1); out = leaky(GAT(t, W4), 0.1) ----
  k_bn_stats<<<gBN, HID, 0, stream>>>(bufB, PST[1]);
  k_final_gemm<<<gWav, B256, 0, stream>>>(bufB, PST[1], gam + 3 * HID, bet + 3 * HID,
                                          W4, a4s, a4d, h4, asrc, adst);
  k_final_agg<<<gWav, B256, 0, stream>>>(h4, asrc, adst, row_ptr, csr_src, b4, out);
}